// Round 3
// baseline (599.187 us; speedup 1.0000x reference)
//
#include <hip/hip_runtime.h>

#define N_NODES 100000
#define NREL 6
#define NEDGE 400000
#define FDIM 128
#define HID 128

constexpr int RN = NREL * N_NODES;   // 600000
constexpr int NBIN = 391;            // ceil(100000 / 256) node bins of 256
constexpr int BINCAP = 1280;         // staging entries per (rel,bin); mean 1024, +8 sigma
constexpr int CSRCAP = 2304;         // int2 CSR entries per (rel,bin); max 1280+768 padded
constexpr int CHUNK = 8192;          // edges per phase-1 block
constexpr int NCHUNK = (NEDGE + CHUNK - 1) / CHUNK;  // 49

// k_prep block-range dispatch
constexpr int NB_XC = (N_NODES * 32) / 256;           // 12500 (exact)
constexpr int NB_WC = (NREL * FDIM * HID) / 256;      // 384 (exact)
constexpr int PREP_BLOCKS = NB_XC + NB_WC + NREL + 1;

typedef __attribute__((ext_vector_type(8))) short short8;
typedef __attribute__((ext_vector_type(4))) float f32x4;

__device__ __forceinline__ unsigned short f2bf(float f) {
  union { float f; unsigned int u; } v; v.f = f;
  unsigned int u = v.u;
  unsigned int r = (u + 0x7FFFu + ((u >> 16) & 1u)) >> 16;
  return (unsigned short)r;
}
__device__ __forceinline__ float bflo(unsigned int w) {
  union { unsigned int u; float f; } v; v.u = w << 16; return v.f;
}
__device__ __forceinline__ float bfhi(unsigned int w) {
  union { unsigned int u; float f; } v; v.u = w & 0xffff0000u; return v.f;
}

// ---------------- zero (cursors + mv only; tiny) ----------------
__global__ void k_zero(unsigned int* __restrict__ p, int nwords) {
  int id = blockIdx.x * blockDim.x + threadIdx.x;
  if (id < nwords) p[id] = 0u;
}

// ---------------- phase 1: LDS-binned staging, both directions ----------------
__global__ __launch_bounds__(256) void k_phase1(
    const int* __restrict__ src, const int* __restrict__ dst,
    int* __restrict__ gCurIn, int* __restrict__ gCurOut,
    unsigned int* __restrict__ stIn, unsigned int* __restrict__ stOut) {
  __shared__ int hIn[NBIN], hOut[NBIN], bIn[NBIN], bOut[NBIN];
  const int r = blockIdx.x / NCHUNK;
  const int c = blockIdx.x % NCHUNK;
  const int t = threadIdx.x;
  for (int i = t; i < NBIN; i += 256) { hIn[i] = 0; hOut[i] = 0; }
  __syncthreads();
  const int base = c * CHUNK;
  const int lim = min(CHUNK, NEDGE - base);
  const int* __restrict__ sR = src + r * NEDGE + base;
  const int* __restrict__ dR = dst + r * NEDGE + base;
  for (int i = t; i < lim; i += 256) {
    atomicAdd(&hIn[dR[i] >> 8], 1);
    atomicAdd(&hOut[sR[i] >> 8], 1);
  }
  __syncthreads();
  for (int i = t; i < NBIN; i += 256) {
    bIn[i]  = atomicAdd(&gCurIn[r * NBIN + i], hIn[i]);
    bOut[i] = atomicAdd(&gCurOut[r * NBIN + i], hOut[i]);
    hIn[i] = 0; hOut[i] = 0;
  }
  __syncthreads();
  for (int i = t; i < lim; i += 256) {
    const int s = sR[i], d = dR[i];
    const int bi = d >> 8, bo = s >> 8;
    const int pi = bIn[bi] + atomicAdd(&hIn[bi], 1);
    const int po = bOut[bo] + atomicAdd(&hOut[bo], 1);
    // pack: bits 17..24 = node-local (0..255), bits 0..16 = other endpoint
    if (pi < BINCAP)
      stIn[(size_t)(r * NBIN + bi) * BINCAP + pi] = ((unsigned)(d & 255) << 17) | (unsigned)s;
    if (po < BINCAP)
      stOut[(size_t)(r * NBIN + bo) * BINCAP + po] = ((unsigned)(s & 255) << 17) | (unsigned)d;
  }
}

// ---------------- phase 2a: out-degree count -> ns ----------------
__global__ __launch_bounds__(256) void k_p2a(const unsigned int* __restrict__ stOut,
                                             const int* __restrict__ gCurOut,
                                             float* __restrict__ ns) {
  __shared__ int cnt[256];
  const int rb = blockIdx.x;
  const int r = rb / NBIN, b = rb % NBIN;
  const int t = threadIdx.x;
  cnt[t] = 0;
  __syncthreads();
  const int m = min(gCurOut[rb], BINCAP);
  const unsigned int* __restrict__ st = stOut + (size_t)rb * BINCAP;
  for (int i = t; i < m; i += 256) atomicAdd(&cnt[st[i] >> 17], 1);
  __syncthreads();
  const int n = b * 256 + t;
  if (n < N_NODES) ns[r * N_NODES + n] = cnt[t] > 0 ? rsqrtf((float)cnt[t]) : 0.f;
}

// ---------------- phase 2b: in-count + scan -> meta, nd, dense padded CSR ----------------
__global__ __launch_bounds__(256) void k_p2in(const unsigned int* __restrict__ stIn,
                                              const int* __restrict__ gCurIn,
                                              const float* __restrict__ ns,
                                              int4* __restrict__ meta,
                                              float* __restrict__ ndA,
                                              int2* __restrict__ csr) {
  __shared__ int cnt[256], offs[256];
  __shared__ int wsum[4];
  const int rb = blockIdx.x;
  const int r = rb / NBIN, b = rb % NBIN;
  const int t = threadIdx.x;
  cnt[t] = 0;
  __syncthreads();
  const int m = min(gCurIn[rb], BINCAP);
  const unsigned int* __restrict__ st = stIn + (size_t)rb * BINCAP;
  for (int i = t; i < m; i += 256) atomicAdd(&cnt[st[i] >> 17], 1);
  __syncthreads();
  // exclusive scan of quad-padded counts
  const int lane = t & 63, wid = t >> 6;
  const int pc = (cnt[t] + 3) & ~3;
  int sum = pc;
#pragma unroll
  for (int o = 1; o < 64; o <<= 1) {
    int y = __shfl_up(sum, o);
    if (lane >= o) sum += y;
  }
  if (lane == 63) wsum[wid] = sum;
  __syncthreads();
  int wadd = 0;
  for (int w = 0; w < wid; ++w) wadd += wsum[w];
  offs[t] = sum - pc + wadd;
  __syncthreads();
  const int n = b * 256 + t;
  const int binBase = rb * CSRCAP;
  if (n < N_NODES) {
    const int d = cnt[t];
    const float nd = d > 0 ? rsqrtf((float)d) : 0.f;
    meta[r * N_NODES + n] = make_int4(d, binBase + offs[t], __float_as_int(nd), 0);
    ndA[r * N_NODES + n] = nd;
    int2* __restrict__ c = csr + binBase + offs[t];
    for (int e = d; e < ((d + 3) & ~3); ++e) c[e] = make_int2(0, 0);  // zero pads
  }
  __syncthreads();
  cnt[t] = 0;  // reuse as scatter cursors
  __syncthreads();
  const float* __restrict__ nsr = ns + r * N_NODES;
  for (int i = t; i < m; i += 256) {
    const unsigned int v = st[i];
    const int local = v >> 17;
    const int s = v & 0x1FFFF;
    const int pos = offs[local] + atomicAdd(&cnt[local], 1);
    csr[binBase + pos] = make_int2(s, __float_as_int(nsr[s]));
  }
}

// ---------------- phase 2c: coef = sum nd[dst] over out-edges -> wmv = ns*coef ----------------
__global__ __launch_bounds__(256) void k_p2b(const unsigned int* __restrict__ stOut,
                                             const int* __restrict__ gCurOut,
                                             const float* __restrict__ ns,
                                             const float* __restrict__ ndA,
                                             float* __restrict__ wmv) {
  __shared__ float fc[256];
  const int rb = blockIdx.x;
  const int r = rb / NBIN, b = rb % NBIN;
  const int t = threadIdx.x;
  fc[t] = 0.f;
  __syncthreads();
  const int m = min(gCurOut[rb], BINCAP);
  const unsigned int* __restrict__ st = stOut + (size_t)rb * BINCAP;
  const float* __restrict__ ndr = ndA + r * N_NODES;
  for (int i = t; i < m; i += 256) {
    const unsigned int v = st[i];
    atomicAdd(&fc[v >> 17], ndr[v & 0x1FFFF]);
  }
  __syncthreads();
  const int n = b * 256 + t;
  if (n < N_NODES) {
    const int rn = r * N_NODES + n;
    wmv[rn] = fc[t] * ns[rn];
  }
}

// ---------------- fused prep: x->bf16 | W1 transpose | u | biases ----------------
__global__ __launch_bounds__(256) void k_prep(
    const float* __restrict__ x, unsigned short* __restrict__ xb,
    const float* __restrict__ W1, const float* __restrict__ b1,
    const float* __restrict__ b2,
    unsigned short* __restrict__ W1T, float* __restrict__ bias1,
    float* __restrict__ bias2,
    const float* __restrict__ W2, const float* __restrict__ Wc,
    float* __restrict__ u) {
  const int b = blockIdx.x;
  const int t = threadIdx.x;
  if (b < NB_XC) {
    const int id = b * 256 + t;
    const float4 v = ((const float4*)x)[id];
    ushort4 o;
    o.x = f2bf(v.x); o.y = f2bf(v.y); o.z = f2bf(v.z); o.w = f2bf(v.w);
    ((ushort4*)xb)[id] = o;
  } else if (b < NB_XC + NB_WC) {
    const int id = (b - NB_XC) * 256 + t;
    const int r = id >> 14;
    const int rem = id & 16383;
    const int j = rem >> 7;
    const int k = rem & 127;
    W1T[id] = f2bf(W1[r * 16384 + k * 128 + j]);
  } else if (b < NB_XC + NB_WC + NREL) {
    const int r = b - (NB_XC + NB_WC);
    const int k = t >> 1;
    const int c = t & 1;
    const float* __restrict__ row = W2 + r * (HID * HID) + k * HID;
    float s = 0.f;
#pragma unroll 8
    for (int j = 0; j < HID; ++j) s = fmaf(row[j], Wc[j * 2 + c], s);
    u[(r * HID + k) * 2 + c] = s;
  } else {
    if (t < HID) {
      float s1 = 0.f, s2 = 0.f;
      for (int r = 0; r < NREL; ++r) {
        s1 += b1[r * HID + t];
        s2 += b2[r * HID + t];
      }
      bias1[t] = s1;
      bias2[t] = s2;
    }
  }
}

// ---------------- fused layer-1: 4-pass-fused branchless edge loop, MFMA ----------------
// Round-2 lesson: gfx950 unified register file -- occupancy band is set by
// VGPR_Count + AGPR (32 here). 100+32=132 landed past the 128 boundary ->
// 2 waves/SIMD (19% occupancy). launch_bounds(256,4) forces VGPR<=96 so
// total <=128 -> 4 waves/SIMD. To give the allocator slack: meta is reloaded
// per rel (no mt/mtn carry; L2-hit, hidden at 4 waves) and dmax uses d4-max
// + 2 shfl_xor instead of the 6-step butterfly. Scheduling left free: at a
// 96-reg budget the compiler serializes gathers into smaller batches, which
// is the right trade (4 waves x ~8 in flight > 2 waves x ~12).
// Inactive passes predicated via cndmask on BOTH weight (0.0f) and gather
// address (node-0 row); never multiply-by-zero on raw CSR payloads (round-1).
__global__ __launch_bounds__(256, 4) void k_layer1(
    const unsigned short* __restrict__ xb,      // [N][128] bf16
    const int2* __restrict__ csr_ew,            // bin-region CSR {src, w}
    const int4* __restrict__ meta,              // [R][N] {d, absOff, nd_bits, -}
    const unsigned short* __restrict__ W1T,     // [R][128][128] bf16 (out, in)
    const float* __restrict__ bias1,
    unsigned short* __restrict__ h)             // [N][128] bf16
{
  __shared__ unsigned short zA[4][16][136];     // per-wave private slices
  const int tid = threadIdx.x;
  const int wave = tid >> 6;
  const int lane = tid & 63;
  const int sub = lane >> 4;
  const int flane = lane & 15;
  const int wnb = blockIdx.x * 64 + wave * 16;

  f32x4 acc[8];
#pragma unroll
  for (int t = 0; t < 8; ++t) acc[t] = (f32x4){0.f, 0.f, 0.f, 0.f};

  const int pn = wnb + flane;
  const bool pok = pn < N_NODES;
  const int pnc = pok ? pn : (N_NODES - 1);

  const unsigned fo = (unsigned)(flane << 3);   // ushort offset within a 128-feat row

  for (int r = 0; r < NREL; ++r) {
    int4 mt = meta[r * N_NODES + pnc];
    if (!pok) { mt.x = 0; mt.z = 0; }
    // per-pass row params (pass p of this wave handles rows p*4+sub)
    int d4[4], o4[4];
    float nd4[4];
#pragma unroll
    for (int p = 0; p < 4; ++p) {
      const int row = p * 4 + sub;
      d4[p] = __shfl(mt.x, row);
      o4[p] = __shfl(mt.y, row);
      nd4[p] = __int_as_float(__shfl(mt.z, row));
    }
    // wave-uniform max degree: per-lane max of its 4 rows, then combine subs
    int dmax = max(max(d4[0], d4[1]), max(d4[2], d4[3]));
    dmax = max(dmax, __shfl_xor(dmax, 16));
    dmax = max(dmax, __shfl_xor(dmax, 32));
    const int nbmax = (dmax + 3) >> 2;

    float b[4][8];
#pragma unroll
    for (int p = 0; p < 4; ++p)
#pragma unroll
      for (int k = 0; k < 8; ++k) b[p][k] = 0.f;

    // preload CSR quads for bi=0 (always-valid memory; garbage contents for
    // d=0 rows are never consumed -- act-predication below)
    uint4 qa[4], qb[4];
#pragma unroll
    for (int p = 0; p < 4; ++p) {
      const uint4* __restrict__ lst = (const uint4*)(csr_ew + o4[p]);
      qa[p] = lst[0];
      qb[p] = lst[1];
    }

    for (int bi = 0; bi < nbmax; ++bi) {
      // predicated weight + gather-address extraction (cndmask, no branches)
      float w0[4], w1[4], w2[4], w3[4];
      unsigned a0[4], a1[4], a2[4], a3[4];
#pragma unroll
      for (int p = 0; p < 4; ++p) {
        const bool act = bi < ((d4[p] + 3) >> 2);
        w0[p] = act ? __uint_as_float(qa[p].y) : 0.f;
        w1[p] = act ? __uint_as_float(qa[p].w) : 0.f;
        w2[p] = act ? __uint_as_float(qb[p].y) : 0.f;
        w3[p] = act ? __uint_as_float(qb[p].w) : 0.f;
        a0[p] = act ? (((unsigned)qa[p].x << 7) + fo) : fo;
        a1[p] = act ? (((unsigned)qa[p].z << 7) + fo) : fo;
        a2[p] = act ? (((unsigned)qb[p].x << 7) + fo) : fo;
        a3[p] = act ? (((unsigned)qb[p].z << 7) + fo) : fo;
      }
      // issue gathers
      uint4 v0[4], v1[4], v2[4], v3[4];
#pragma unroll
      for (int p = 0; p < 4; ++p) {
        v0[p] = *(const uint4*)(xb + a0[p]);
        v1[p] = *(const uint4*)(xb + a1[p]);
        v2[p] = *(const uint4*)(xb + a2[p]);
        v3[p] = *(const uint4*)(xb + a3[p]);
      }
      // software-pipeline: CSR quads for bi+1 (clamped to quad 0 when done;
      // valid memory, data never used)
#pragma unroll
      for (int p = 0; p < 4; ++p) {
        const int nb_p = (d4[p] + 3) >> 2;
        const int bn = bi + 1;
        const int qoff = o4[p] + ((bn < nb_p) ? (bn << 2) : 0);
        const uint4* __restrict__ lst = (const uint4*)(csr_ew + qoff);
        qa[p] = lst[0];
        qb[p] = lst[1];
      }
      // FMAs
#pragma unroll
      for (int p = 0; p < 4; ++p) {
#define ACC8(V, W) \
        b[p][0] = fmaf(bflo(V.x), W, b[p][0]); b[p][1] = fmaf(bfhi(V.x), W, b[p][1]); \
        b[p][2] = fmaf(bflo(V.y), W, b[p][2]); b[p][3] = fmaf(bfhi(V.y), W, b[p][3]); \
        b[p][4] = fmaf(bflo(V.z), W, b[p][4]); b[p][5] = fmaf(bfhi(V.z), W, b[p][5]); \
        b[p][6] = fmaf(bflo(V.w), W, b[p][6]); b[p][7] = fmaf(bfhi(V.w), W, b[p][7]);
        ACC8(v0[p], w0[p]) ACC8(v1[p], w1[p]) ACC8(v2[p], w2[p]) ACC8(v3[p], w3[p])
#undef ACC8
      }
    }

    // pack aggregated rows into zA
#pragma unroll
    for (int p = 0; p < 4; ++p) {
      const int row = p * 4 + sub;
      const float nd = nd4[p];
      uint4 pk;
      pk.x = (unsigned)f2bf(b[p][0] * nd) | ((unsigned)f2bf(b[p][1] * nd) << 16);
      pk.y = (unsigned)f2bf(b[p][2] * nd) | ((unsigned)f2bf(b[p][3] * nd) << 16);
      pk.z = (unsigned)f2bf(b[p][4] * nd) | ((unsigned)f2bf(b[p][5] * nd) << 16);
      pk.w = (unsigned)f2bf(b[p][6] * nd) | ((unsigned)f2bf(b[p][7] * nd) << 16);
      *(uint4*)(&zA[wave][row][flane * 8]) = pk;
    }
    const int m = lane & 15;
    const int qq = lane >> 4;
    const unsigned short* __restrict__ wr = W1T + r * (FDIM * HID);
#pragma unroll
    for (int kk = 0; kk < 4; ++kk) {
      const short8 af = *(const short8*)(&zA[wave][m][kk * 32 + qq * 8]);
#pragma unroll
      for (int t = 0; t < 8; ++t) {
        const short8 bfr = *(const short8*)(wr + (t * 16 + m) * 128 + kk * 32 + qq * 8);
        acc[t] = __builtin_amdgcn_mfma_f32_16x16x32_bf16(af, bfr, acc[t], 0, 0, 0);
      }
    }
  }

  // epilogue: bias+relu, stage through zA (free after last MFMA; same-wave so
  // no barrier needed), then 16B-coalesced global stores
  const int col = lane & 15;
  const int rq = (lane >> 4) * 4;
#pragma unroll
  for (int t = 0; t < 8; ++t) {
    const float bsv = bias1[t * 16 + col];
#pragma unroll
    for (int rr = 0; rr < 4; ++rr) {
      float v = acc[t][rr] + bsv;
      v = fmaxf(v, 0.f);
      zA[wave][rq + rr][t * 16 + col] = f2bf(v);
    }
  }
#pragma unroll
  for (int rr2 = 0; rr2 < 4; ++rr2) {
    const int row = rr2 * 4 + sub;
    const int node = wnb + row;
    if (node < N_NODES) {
      const uint4 hv = *(const uint4*)(&zA[wave][row][flane * 8]);
      *(uint4*)(h + ((size_t)node << 7) + fo) = hv;
    }
  }
}

// ---------------- layer-2 folded: dense h stream with precomputed weights ----------------
__global__ __launch_bounds__(256) void k_mv(const unsigned short* __restrict__ h,
                                            const float* __restrict__ wmv,
                                            float* __restrict__ mv) {
  __shared__ float sh[16][136];
  const int sub = threadIdx.x >> 4;
  const int flane = threadIdx.x & 15;
  const unsigned fo = (unsigned)(flane << 3);
  float acc[NREL][8];
#pragma unroll
  for (int r = 0; r < NREL; ++r)
#pragma unroll
    for (int k = 0; k < 8; ++k) acc[r][k] = 0.f;
  const int nbase = blockIdx.x * 256 + sub * 16;
  for (int i = 0; i < 16; ++i) {
    const int n = nbase + i;
    if (n >= N_NODES) break;
    const uint4 hv = *(const uint4*)(h + ((size_t)n << 7) + fo);
    float hf[8];
    hf[0] = bflo(hv.x); hf[1] = bfhi(hv.x); hf[2] = bflo(hv.y); hf[3] = bfhi(hv.y);
    hf[4] = bflo(hv.z); hf[5] = bfhi(hv.z); hf[6] = bflo(hv.w); hf[7] = bfhi(hv.w);
#pragma unroll
    for (int r = 0; r < NREL; ++r) {
      const float w = wmv[r * N_NODES + n];
#pragma unroll
      for (int k = 0; k < 8; ++k) acc[r][k] = fmaf(w, hf[k], acc[r][k]);
    }
  }
  const float inv = 1.0f / (float)N_NODES;
  const int t = threadIdx.x;
#pragma unroll
  for (int r = 0; r < NREL; ++r) {
    __syncthreads();
#pragma unroll
    for (int k = 0; k < 8; ++k) sh[sub][flane * 8 + k] = acc[r][k];
    __syncthreads();
    if (t < 128) {
      float s = 0.f;
#pragma unroll
      for (int j = 0; j < 16; ++j) s += sh[j][t];
      atomicAdd(&mv[r * HID + t], s * inv);
    }
  }
}

// ---------------- final ----------------
__global__ __launch_bounds__(256) void k_final(const float* __restrict__ mv,
                                               const float* __restrict__ u,
                                               const float* __restrict__ bias2,
                                               const float* __restrict__ Wc,
                                               const float* __restrict__ bc,
                                               float* __restrict__ out) {
  __shared__ float r0[256], r1[256];
  const int t = threadIdx.x;
  float s0 = 0.f, s1 = 0.f;
  for (int rk = t; rk < NREL * HID; rk += 256) {
    const float m = mv[rk];
    s0 = fmaf(m, u[rk * 2], s0);
    s1 = fmaf(m, u[rk * 2 + 1], s1);
  }
  r0[t] = s0; r1[t] = s1;
  __syncthreads();
  for (int off = 128; off > 0; off >>= 1) {
    if (t < off) { r0[t] += r0[t + off]; r1[t] += r1[t + off]; }
    __syncthreads();
  }
  if (t == 0) {
    float t0 = bc[0], t1 = bc[1];
    for (int j = 0; j < HID; ++j) {
      const float b = bias2[j];
      t0 = fmaf(b, Wc[j * 2], t0);
      t1 = fmaf(b, Wc[j * 2 + 1], t1);
    }
    out[0] = r0[0] + t0;
    out[1] = r1[0] + t1;
  }
}

extern "C" void kernel_launch(void* const* d_in, const int* in_sizes, int n_in,
                              void* d_out, int out_size, void* d_ws, size_t ws_size,
                              hipStream_t stream) {
  (void)in_sizes; (void)n_in; (void)out_size; (void)ws_size;
  const float* x   = (const float*)d_in[0];
  const int* esrc  = (const int*)d_in[1];
  const int* edst  = (const int*)d_in[2];
  const float* W1  = (const float*)d_in[3];
  const float* b1  = (const float*)d_in[4];
  const float* W2  = (const float*)d_in[5];
  const float* b2  = (const float*)d_in[6];
  const float* Wc  = (const float*)d_in[7];
  const float* bc  = (const float*)d_in[8];
  float* out = (float*)d_out;

  char* p = (char*)d_ws;
  size_t off = 0;
  auto take = [&](size_t bytes) -> void* {
    void* q = p + off;
    off += (bytes + 255) & ~(size_t)255;
    return q;
  };
  // ---- zeroed region (cursors + mv; ~22 KB) ----
  int*   gCurIn  = (int*)take((size_t)NREL * NBIN * 4);
  int*   gCurOut = (int*)take((size_t)NREL * NBIN * 4);
  float* mv      = (float*)take((size_t)NREL * HID * 4);
  const size_t zero_bytes = off;
  // ---- non-zeroed region ----
  float* ns   = (float*)take((size_t)RN * 4);
  float* ndA  = (float*)take((size_t)RN * 4);
  float* wmv  = (float*)take((size_t)RN * 4);
  int4*  meta = (int4*)take((size_t)RN * 16);
  unsigned int* stIn  = (unsigned int*)take((size_t)NREL * NBIN * BINCAP * 4);  // 12 MB
  unsigned int* stOut = (unsigned int*)take((size_t)NREL * NBIN * BINCAP * 4);  // 12 MB
  int2* csr = (int2*)take((size_t)NREL * NBIN * CSRCAP * 8);                    // 43 MB
  unsigned short* W1T = (unsigned short*)take((size_t)NREL * FDIM * HID * 2);
  float* bias1 = (float*)take(HID * 4);
  float* bias2 = (float*)take(HID * 4);
  float* u     = (float*)take((size_t)NREL * HID * 2 * 4);
  unsigned short* h  = (unsigned short*)take((size_t)N_NODES * FDIM * 2);
  unsigned short* xb = (unsigned short*)take((size_t)N_NODES * FDIM * 2);

  const int zero_words = (int)(zero_bytes / 4);
  k_zero<<<(zero_words + 255) / 256, 256, 0, stream>>>((unsigned int*)d_ws, zero_words);
  k_phase1<<<NREL * NCHUNK, 256, 0, stream>>>(esrc, edst, gCurIn, gCurOut, stIn, stOut);
  k_p2a<<<NREL * NBIN, 256, 0, stream>>>(stOut, gCurOut, ns);
  k_p2in<<<NREL * NBIN, 256, 0, stream>>>(stIn, gCurIn, ns, meta, ndA, csr);
  k_p2b<<<NREL * NBIN, 256, 0, stream>>>(stOut, gCurOut, ns, ndA, wmv);
  k_prep<<<PREP_BLOCKS, 256, 0, stream>>>(x, xb, W1, b1, b2, W1T, bias1, bias2, W2, Wc, u);
  k_layer1<<<(N_NODES + 63) / 64, 256, 0, stream>>>(xb, csr, meta, W1T, bias1, h);
  k_mv<<<(N_NODES + 255) / 256, 256, 0, stream>>>(h, wmv, mv);
  k_final<<<1, 256, 0, stream>>>(mv, u, bias2, Wc, bc, out);
}

// Round 4
// 536.794 us; speedup vs baseline: 1.1162x; 1.1162x over previous
//
#include <hip/hip_runtime.h>

#define N_NODES 100000
#define NREL 6
#define NEDGE 400000
#define FDIM 128
#define HID 128

constexpr int RN = NREL * N_NODES;   // 600000
constexpr int NBIN = 391;            // ceil(100000 / 256) node bins of 256
constexpr int BINCAP = 1280;         // staging entries per (rel,bin); mean 1024, +8 sigma
constexpr int CSRCAP = 2304;         // int2 CSR entries per (rel,bin); max 1280+768 padded
constexpr int CHUNK = 8192;          // edges per phase-1 block
constexpr int NCHUNK = (NEDGE + CHUNK - 1) / CHUNK;  // 49

// k_prep block-range dispatch
constexpr int NB_XC = (N_NODES * 32) / 256;           // 12500 (exact)
constexpr int NB_WC = (NREL * FDIM * HID) / 256;      // 384 (exact)
constexpr int PREP_BLOCKS = NB_XC + NB_WC + NREL + 1;

typedef __attribute__((ext_vector_type(8))) short short8;
typedef __attribute__((ext_vector_type(4))) float f32x4;

__device__ __forceinline__ unsigned short f2bf(float f) {
  union { float f; unsigned int u; } v; v.f = f;
  unsigned int u = v.u;
  unsigned int r = (u + 0x7FFFu + ((u >> 16) & 1u)) >> 16;
  return (unsigned short)r;
}
__device__ __forceinline__ float bflo(unsigned int w) {
  union { unsigned int u; float f; } v; v.u = w << 16; return v.f;
}
__device__ __forceinline__ float bfhi(unsigned int w) {
  union { unsigned int u; float f; } v; v.u = w & 0xffff0000u; return v.f;
}

// ---------------- zero (cursors + mv only; tiny) ----------------
__global__ void k_zero(unsigned int* __restrict__ p, int nwords) {
  int id = blockIdx.x * blockDim.x + threadIdx.x;
  if (id < nwords) p[id] = 0u;
}

// ---------------- phase 1: LDS-binned staging, both directions ----------------
__global__ __launch_bounds__(256) void k_phase1(
    const int* __restrict__ src, const int* __restrict__ dst,
    int* __restrict__ gCurIn, int* __restrict__ gCurOut,
    unsigned int* __restrict__ stIn, unsigned int* __restrict__ stOut) {
  __shared__ int hIn[NBIN], hOut[NBIN], bIn[NBIN], bOut[NBIN];
  const int r = blockIdx.x / NCHUNK;
  const int c = blockIdx.x % NCHUNK;
  const int t = threadIdx.x;
  for (int i = t; i < NBIN; i += 256) { hIn[i] = 0; hOut[i] = 0; }
  __syncthreads();
  const int base = c * CHUNK;
  const int lim = min(CHUNK, NEDGE - base);
  const int* __restrict__ sR = src + r * NEDGE + base;
  const int* __restrict__ dR = dst + r * NEDGE + base;
  for (int i = t; i < lim; i += 256) {
    atomicAdd(&hIn[dR[i] >> 8], 1);
    atomicAdd(&hOut[sR[i] >> 8], 1);
  }
  __syncthreads();
  for (int i = t; i < NBIN; i += 256) {
    bIn[i]  = atomicAdd(&gCurIn[r * NBIN + i], hIn[i]);
    bOut[i] = atomicAdd(&gCurOut[r * NBIN + i], hOut[i]);
    hIn[i] = 0; hOut[i] = 0;
  }
  __syncthreads();
  for (int i = t; i < lim; i += 256) {
    const int s = sR[i], d = dR[i];
    const int bi = d >> 8, bo = s >> 8;
    const int pi = bIn[bi] + atomicAdd(&hIn[bi], 1);
    const int po = bOut[bo] + atomicAdd(&hOut[bo], 1);
    // pack: bits 17..24 = node-local (0..255), bits 0..16 = other endpoint
    if (pi < BINCAP)
      stIn[(size_t)(r * NBIN + bi) * BINCAP + pi] = ((unsigned)(d & 255) << 17) | (unsigned)s;
    if (po < BINCAP)
      stOut[(size_t)(r * NBIN + bo) * BINCAP + po] = ((unsigned)(s & 255) << 17) | (unsigned)d;
  }
}

// ---------------- phase 2a: out-degree count -> ns ----------------
__global__ __launch_bounds__(256) void k_p2a(const unsigned int* __restrict__ stOut,
                                             const int* __restrict__ gCurOut,
                                             float* __restrict__ ns) {
  __shared__ int cnt[256];
  const int rb = blockIdx.x;
  const int r = rb / NBIN, b = rb % NBIN;
  const int t = threadIdx.x;
  cnt[t] = 0;
  __syncthreads();
  const int m = min(gCurOut[rb], BINCAP);
  const unsigned int* __restrict__ st = stOut + (size_t)rb * BINCAP;
  for (int i = t; i < m; i += 256) atomicAdd(&cnt[st[i] >> 17], 1);
  __syncthreads();
  const int n = b * 256 + t;
  if (n < N_NODES) ns[r * N_NODES + n] = cnt[t] > 0 ? rsqrtf((float)cnt[t]) : 0.f;
}

// ---------------- phase 2b: in-count + scan -> meta, nd, dense padded CSR ----------------
__global__ __launch_bounds__(256) void k_p2in(const unsigned int* __restrict__ stIn,
                                              const int* __restrict__ gCurIn,
                                              const float* __restrict__ ns,
                                              int4* __restrict__ meta,
                                              float* __restrict__ ndA,
                                              int2* __restrict__ csr) {
  __shared__ int cnt[256], offs[256];
  __shared__ int wsum[4];
  const int rb = blockIdx.x;
  const int r = rb / NBIN, b = rb % NBIN;
  const int t = threadIdx.x;
  cnt[t] = 0;
  __syncthreads();
  const int m = min(gCurIn[rb], BINCAP);
  const unsigned int* __restrict__ st = stIn + (size_t)rb * BINCAP;
  for (int i = t; i < m; i += 256) atomicAdd(&cnt[st[i] >> 17], 1);
  __syncthreads();
  // exclusive scan of quad-padded counts
  const int lane = t & 63, wid = t >> 6;
  const int pc = (cnt[t] + 3) & ~3;
  int sum = pc;
#pragma unroll
  for (int o = 1; o < 64; o <<= 1) {
    int y = __shfl_up(sum, o);
    if (lane >= o) sum += y;
  }
  if (lane == 63) wsum[wid] = sum;
  __syncthreads();
  int wadd = 0;
  for (int w = 0; w < wid; ++w) wadd += wsum[w];
  offs[t] = sum - pc + wadd;
  __syncthreads();
  const int n = b * 256 + t;
  const int binBase = rb * CSRCAP;
  if (n < N_NODES) {
    const int d = cnt[t];
    const float nd = d > 0 ? rsqrtf((float)d) : 0.f;
    meta[r * N_NODES + n] = make_int4(d, binBase + offs[t], __float_as_int(nd), 0);
    ndA[r * N_NODES + n] = nd;
    int2* __restrict__ c = csr + binBase + offs[t];
    for (int e = d; e < ((d + 3) & ~3); ++e) c[e] = make_int2(0, 0);  // zero pads
  }
  __syncthreads();
  cnt[t] = 0;  // reuse as scatter cursors
  __syncthreads();
  const float* __restrict__ nsr = ns + r * N_NODES;
  for (int i = t; i < m; i += 256) {
    const unsigned int v = st[i];
    const int local = v >> 17;
    const int s = v & 0x1FFFF;
    const int pos = offs[local] + atomicAdd(&cnt[local], 1);
    csr[binBase + pos] = make_int2(s, __float_as_int(nsr[s]));
  }
}

// ---------------- phase 2c: coef = sum nd[dst] over out-edges -> wmv = ns*coef ----------------
__global__ __launch_bounds__(256) void k_p2b(const unsigned int* __restrict__ stOut,
                                             const int* __restrict__ gCurOut,
                                             const float* __restrict__ ns,
                                             const float* __restrict__ ndA,
                                             float* __restrict__ wmv) {
  __shared__ float fc[256];
  const int rb = blockIdx.x;
  const int r = rb / NBIN, b = rb % NBIN;
  const int t = threadIdx.x;
  fc[t] = 0.f;
  __syncthreads();
  const int m = min(gCurOut[rb], BINCAP);
  const unsigned int* __restrict__ st = stOut + (size_t)rb * BINCAP;
  const float* __restrict__ ndr = ndA + r * N_NODES;
  for (int i = t; i < m; i += 256) {
    const unsigned int v = st[i];
    atomicAdd(&fc[v >> 17], ndr[v & 0x1FFFF]);
  }
  __syncthreads();
  const int n = b * 256 + t;
  if (n < N_NODES) {
    const int rn = r * N_NODES + n;
    wmv[rn] = fc[t] * ns[rn];
  }
}

// ---------------- fused prep: x->bf16 | W1 transpose | u | biases ----------------
__global__ __launch_bounds__(256) void k_prep(
    const float* __restrict__ x, unsigned short* __restrict__ xb,
    const float* __restrict__ W1, const float* __restrict__ b1,
    const float* __restrict__ b2,
    unsigned short* __restrict__ W1T, float* __restrict__ bias1,
    float* __restrict__ bias2,
    const float* __restrict__ W2, const float* __restrict__ Wc,
    float* __restrict__ u) {
  const int b = blockIdx.x;
  const int t = threadIdx.x;
  if (b < NB_XC) {
    const int id = b * 256 + t;
    const float4 v = ((const float4*)x)[id];
    ushort4 o;
    o.x = f2bf(v.x); o.y = f2bf(v.y); o.z = f2bf(v.z); o.w = f2bf(v.w);
    ((ushort4*)xb)[id] = o;
  } else if (b < NB_XC + NB_WC) {
    const int id = (b - NB_XC) * 256 + t;
    const int r = id >> 14;
    const int rem = id & 16383;
    const int j = rem >> 7;
    const int k = rem & 127;
    W1T[id] = f2bf(W1[r * 16384 + k * 128 + j]);
  } else if (b < NB_XC + NB_WC + NREL) {
    const int r = b - (NB_XC + NB_WC);
    const int k = t >> 1;
    const int c = t & 1;
    const float* __restrict__ row = W2 + r * (HID * HID) + k * HID;
    float s = 0.f;
#pragma unroll 8
    for (int j = 0; j < HID; ++j) s = fmaf(row[j], Wc[j * 2 + c], s);
    u[(r * HID + k) * 2 + c] = s;
  } else {
    if (t < HID) {
      float s1 = 0.f, s2 = 0.f;
      for (int r = 0; r < NREL; ++r) {
        s1 += b1[r * HID + t];
        s2 += b2[r * HID + t];
      }
      bias1[t] = s1;
      bias2[t] = s2;
    }
  }
}

// ---------------- fused layer-1: pass-pair edge loop, MFMA ----------------
// Register-demand ladder (rounds 1-3 lessons):
//   - 4-pass bundle demand ~150+ live regs; natural alloc 100V+32A=132 -> 2
//     waves/SIMD (r2, 262us). Forcing (256,4) on it -> scratch spills in the
//     hot loop, WRITE_SIZE 25->404MB, dur 358us (r3). Never force a cap below
//     the hand-counted live set.
//   - This version splits the 16 rows into TWO pass-pairs (pp=0: rows 0-7,
//     pp=1: rows 8-15). Peak live ~= acc32(AGPR) + b16 + qa/qb16 + v32 + w8
//     + meta/misc ~20 ~= 125 <= 128, so (256,4) is satisfiable -> 4
//     waves/SIMD. Per-pair dmax over 8 rows also shrinks predicated waste.
// Inactive passes predicated via cndmask on BOTH weight (0.0f) and gather
// address (node-0 row); never multiply-by-zero on raw CSR payloads (round-1).
__global__ __launch_bounds__(256, 4) void k_layer1(
    const unsigned short* __restrict__ xb,      // [N][128] bf16
    const int2* __restrict__ csr_ew,            // bin-region CSR {src, w}
    const int4* __restrict__ meta,              // [R][N] {d, absOff, nd_bits, -}
    const unsigned short* __restrict__ W1T,     // [R][128][128] bf16 (out, in)
    const float* __restrict__ bias1,
    unsigned short* __restrict__ h)             // [N][128] bf16
{
  __shared__ unsigned short zA[4][16][136];     // per-wave private slices
  const int tid = threadIdx.x;
  const int wave = tid >> 6;
  const int lane = tid & 63;
  const int sub = lane >> 4;
  const int flane = lane & 15;
  const int wnb = blockIdx.x * 64 + wave * 16;

  f32x4 acc[8];
#pragma unroll
  for (int t = 0; t < 8; ++t) acc[t] = (f32x4){0.f, 0.f, 0.f, 0.f};

  const int pn = wnb + flane;
  const bool pok = pn < N_NODES;
  const int pnc = pok ? pn : (N_NODES - 1);

  const unsigned fo = (unsigned)(flane << 3);   // ushort offset within a 128-feat row

  for (int r = 0; r < NREL; ++r) {
    int4 mt = meta[r * N_NODES + pnc];
    if (!pok) { mt.x = 0; mt.z = 0; }

#pragma unroll
    for (int pp = 0; pp < 2; ++pp) {
      // pass p of this pair handles row pp*8 + p*4 + sub
      int d2[2], o2[2];
      float nd2[2];
#pragma unroll
      for (int p = 0; p < 2; ++p) {
        const int row = pp * 8 + p * 4 + sub;
        d2[p] = __shfl(mt.x, row);
        o2[p] = __shfl(mt.y, row);
        nd2[p] = __int_as_float(__shfl(mt.z, row));
      }
      // wave-uniform max degree over this pair's 8 rows
      int dmax = max(d2[0], d2[1]);
      dmax = max(dmax, __shfl_xor(dmax, 16));
      dmax = max(dmax, __shfl_xor(dmax, 32));
      const int nbmax = (dmax + 3) >> 2;

      float b[2][8];
#pragma unroll
      for (int p = 0; p < 2; ++p)
#pragma unroll
        for (int k = 0; k < 8; ++k) b[p][k] = 0.f;

      // preload CSR quads for bi=0 (always-valid memory; garbage contents for
      // d=0 rows never consumed -- act-predication below)
      uint4 qa[2], qb[2];
#pragma unroll
      for (int p = 0; p < 2; ++p) {
        const uint4* __restrict__ lst = (const uint4*)(csr_ew + o2[p]);
        qa[p] = lst[0];
        qb[p] = lst[1];
      }

      for (int bi = 0; bi < nbmax; ++bi) {
        // predicated weight + gather-address extraction (cndmask, no branches)
        float w0[2], w1[2], w2[2], w3[2];
        unsigned a0[2], a1[2], a2[2], a3[2];
#pragma unroll
        for (int p = 0; p < 2; ++p) {
          const bool act = bi < ((d2[p] + 3) >> 2);
          w0[p] = act ? __uint_as_float(qa[p].y) : 0.f;
          w1[p] = act ? __uint_as_float(qa[p].w) : 0.f;
          w2[p] = act ? __uint_as_float(qb[p].y) : 0.f;
          w3[p] = act ? __uint_as_float(qb[p].w) : 0.f;
          a0[p] = act ? (((unsigned)qa[p].x << 7) + fo) : fo;
          a1[p] = act ? (((unsigned)qa[p].z << 7) + fo) : fo;
          a2[p] = act ? (((unsigned)qb[p].x << 7) + fo) : fo;
          a3[p] = act ? (((unsigned)qb[p].z << 7) + fo) : fo;
        }
        // issue the pair's 8 gathers back-to-back
        uint4 v0[2], v1[2], v2[2], v3[2];
#pragma unroll
        for (int p = 0; p < 2; ++p) {
          v0[p] = *(const uint4*)(xb + a0[p]);
          v1[p] = *(const uint4*)(xb + a1[p]);
          v2[p] = *(const uint4*)(xb + a2[p]);
          v3[p] = *(const uint4*)(xb + a3[p]);
        }
        // software-pipeline: CSR quads for bi+1 (clamped to quad 0 when done;
        // valid memory, data never used)
#pragma unroll
        for (int p = 0; p < 2; ++p) {
          const int nb_p = (d2[p] + 3) >> 2;
          const int bn = bi + 1;
          const int qoff = o2[p] + ((bn < nb_p) ? (bn << 2) : 0);
          const uint4* __restrict__ lst = (const uint4*)(csr_ew + qoff);
          qa[p] = lst[0];
          qb[p] = lst[1];
        }
        // FMAs
#pragma unroll
        for (int p = 0; p < 2; ++p) {
#define ACC8(V, W) \
          b[p][0] = fmaf(bflo(V.x), W, b[p][0]); b[p][1] = fmaf(bfhi(V.x), W, b[p][1]); \
          b[p][2] = fmaf(bflo(V.y), W, b[p][2]); b[p][3] = fmaf(bfhi(V.y), W, b[p][3]); \
          b[p][4] = fmaf(bflo(V.z), W, b[p][4]); b[p][5] = fmaf(bfhi(V.z), W, b[p][5]); \
          b[p][6] = fmaf(bflo(V.w), W, b[p][6]); b[p][7] = fmaf(bfhi(V.w), W, b[p][7]);
          ACC8(v0[p], w0[p]) ACC8(v1[p], w1[p]) ACC8(v2[p], w2[p]) ACC8(v3[p], w3[p])
#undef ACC8
        }
      }

      // pack this pair's aggregated rows into zA
#pragma unroll
      for (int p = 0; p < 2; ++p) {
        const int row = pp * 8 + p * 4 + sub;
        const float nd = nd2[p];
        uint4 pk;
        pk.x = (unsigned)f2bf(b[p][0] * nd) | ((unsigned)f2bf(b[p][1] * nd) << 16);
        pk.y = (unsigned)f2bf(b[p][2] * nd) | ((unsigned)f2bf(b[p][3] * nd) << 16);
        pk.z = (unsigned)f2bf(b[p][4] * nd) | ((unsigned)f2bf(b[p][5] * nd) << 16);
        pk.w = (unsigned)f2bf(b[p][6] * nd) | ((unsigned)f2bf(b[p][7] * nd) << 16);
        *(uint4*)(&zA[wave][row][flane * 8]) = pk;
      }
    }

    const int m = lane & 15;
    const int qq = lane >> 4;
    const unsigned short* __restrict__ wr = W1T + r * (FDIM * HID);
#pragma unroll
    for (int kk = 0; kk < 4; ++kk) {
      const short8 af = *(const short8*)(&zA[wave][m][kk * 32 + qq * 8]);
#pragma unroll
      for (int t = 0; t < 8; ++t) {
        const short8 bfr = *(const short8*)(wr + (t * 16 + m) * 128 + kk * 32 + qq * 8);
        acc[t] = __builtin_amdgcn_mfma_f32_16x16x32_bf16(af, bfr, acc[t], 0, 0, 0);
      }
    }
  }

  // epilogue: bias+relu, stage through zA (free after last MFMA; same-wave so
  // no barrier needed), then 16B-coalesced global stores
  const int col = lane & 15;
  const int rq = (lane >> 4) * 4;
#pragma unroll
  for (int t = 0; t < 8; ++t) {
    const float bsv = bias1[t * 16 + col];
#pragma unroll
    for (int rr = 0; rr < 4; ++rr) {
      float v = acc[t][rr] + bsv;
      v = fmaxf(v, 0.f);
      zA[wave][rq + rr][t * 16 + col] = f2bf(v);
    }
  }
#pragma unroll
  for (int rr2 = 0; rr2 < 4; ++rr2) {
    const int row = rr2 * 4 + sub;
    const int node = wnb + row;
    if (node < N_NODES) {
      const uint4 hv = *(const uint4*)(&zA[wave][row][flane * 8]);
      *(uint4*)(h + ((size_t)node << 7) + fo) = hv;
    }
  }
}

// ---------------- layer-2 folded: dense h stream with precomputed weights ----------------
__global__ __launch_bounds__(256) void k_mv(const unsigned short* __restrict__ h,
                                            const float* __restrict__ wmv,
                                            float* __restrict__ mv) {
  __shared__ float sh[16][136];
  const int sub = threadIdx.x >> 4;
  const int flane = threadIdx.x & 15;
  const unsigned fo = (unsigned)(flane << 3);
  float acc[NREL][8];
#pragma unroll
  for (int r = 0; r < NREL; ++r)
#pragma unroll
    for (int k = 0; k < 8; ++k) acc[r][k] = 0.f;
  const int nbase = blockIdx.x * 256 + sub * 16;
  for (int i = 0; i < 16; ++i) {
    const int n = nbase + i;
    if (n >= N_NODES) break;
    const uint4 hv = *(const uint4*)(h + ((size_t)n << 7) + fo);
    float hf[8];
    hf[0] = bflo(hv.x); hf[1] = bfhi(hv.x); hf[2] = bflo(hv.y); hf[3] = bfhi(hv.y);
    hf[4] = bflo(hv.z); hf[5] = bfhi(hv.z); hf[6] = bflo(hv.w); hf[7] = bfhi(hv.w);
#pragma unroll
    for (int r = 0; r < NREL; ++r) {
      const float w = wmv[r * N_NODES + n];
#pragma unroll
      for (int k = 0; k < 8; ++k) acc[r][k] = fmaf(w, hf[k], acc[r][k]);
    }
  }
  const float inv = 1.0f / (float)N_NODES;
  const int t = threadIdx.x;
#pragma unroll
  for (int r = 0; r < NREL; ++r) {
    __syncthreads();
#pragma unroll
    for (int k = 0; k < 8; ++k) sh[sub][flane * 8 + k] = acc[r][k];
    __syncthreads();
    if (t < 128) {
      float s = 0.f;
#pragma unroll
      for (int j = 0; j < 16; ++j) s += sh[j][t];
      atomicAdd(&mv[r * HID + t], s * inv);
    }
  }
}

// ---------------- final ----------------
__global__ __launch_bounds__(256) void k_final(const float* __restrict__ mv,
                                               const float* __restrict__ u,
                                               const float* __restrict__ bias2,
                                               const float* __restrict__ Wc,
                                               const float* __restrict__ bc,
                                               float* __restrict__ out) {
  __shared__ float r0[256], r1[256];
  const int t = threadIdx.x;
  float s0 = 0.f, s1 = 0.f;
  for (int rk = t; rk < NREL * HID; rk += 256) {
    const float m = mv[rk];
    s0 = fmaf(m, u[rk * 2], s0);
    s1 = fmaf(m, u[rk * 2 + 1], s1);
  }
  r0[t] = s0; r1[t] = s1;
  __syncthreads();
  for (int off = 128; off > 0; off >>= 1) {
    if (t < off) { r0[t] += r0[t + off]; r1[t] += r1[t + off]; }
    __syncthreads();
  }
  if (t == 0) {
    float t0 = bc[0], t1 = bc[1];
    for (int j = 0; j < HID; ++j) {
      const float b = bias2[j];
      t0 = fmaf(b, Wc[j * 2], t0);
      t1 = fmaf(b, Wc[j * 2 + 1], t1);
    }
    out[0] = r0[0] + t0;
    out[1] = r1[0] + t1;
  }
}

extern "C" void kernel_launch(void* const* d_in, const int* in_sizes, int n_in,
                              void* d_out, int out_size, void* d_ws, size_t ws_size,
                              hipStream_t stream) {
  (void)in_sizes; (void)n_in; (void)out_size; (void)ws_size;
  const float* x   = (const float*)d_in[0];
  const int* esrc  = (const int*)d_in[1];
  const int* edst  = (const int*)d_in[2];
  const float* W1  = (const float*)d_in[3];
  const float* b1  = (const float*)d_in[4];
  const float* W2  = (const float*)d_in[5];
  const float* b2  = (const float*)d_in[6];
  const float* Wc  = (const float*)d_in[7];
  const float* bc  = (const float*)d_in[8];
  float* out = (float*)d_out;

  char* p = (char*)d_ws;
  size_t off = 0;
  auto take = [&](size_t bytes) -> void* {
    void* q = p + off;
    off += (bytes + 255) & ~(size_t)255;
    return q;
  };
  // ---- zeroed region (cursors + mv; ~22 KB) ----
  int*   gCurIn  = (int*)take((size_t)NREL * NBIN * 4);
  int*   gCurOut = (int*)take((size_t)NREL * NBIN * 4);
  float* mv      = (float*)take((size_t)NREL * HID * 4);
  const size_t zero_bytes = off;
  // ---- non-zeroed region ----
  float* ns   = (float*)take((size_t)RN * 4);
  float* ndA  = (float*)take((size_t)RN * 4);
  float* wmv  = (float*)take((size_t)RN * 4);
  int4*  meta = (int4*)take((size_t)RN * 16);
  unsigned int* stIn  = (unsigned int*)take((size_t)NREL * NBIN * BINCAP * 4);  // 12 MB
  unsigned int* stOut = (unsigned int*)take((size_t)NREL * NBIN * BINCAP * 4);  // 12 MB
  int2* csr = (int2*)take((size_t)NREL * NBIN * CSRCAP * 8);                    // 43 MB
  unsigned short* W1T = (unsigned short*)take((size_t)NREL * FDIM * HID * 2);
  float* bias1 = (float*)take(HID * 4);
  float* bias2 = (float*)take(HID * 4);
  float* u     = (float*)take((size_t)NREL * HID * 2 * 4);
  unsigned short* h  = (unsigned short*)take((size_t)N_NODES * FDIM * 2);
  unsigned short* xb = (unsigned short*)take((size_t)N_NODES * FDIM * 2);

  const int zero_words = (int)(zero_bytes / 4);
  k_zero<<<(zero_words + 255) / 256, 256, 0, stream>>>((unsigned int*)d_ws, zero_words);
  k_phase1<<<NREL * NCHUNK, 256, 0, stream>>>(esrc, edst, gCurIn, gCurOut, stIn, stOut);
  k_p2a<<<NREL * NBIN, 256, 0, stream>>>(stOut, gCurOut, ns);
  k_p2in<<<NREL * NBIN, 256, 0, stream>>>(stIn, gCurIn, ns, meta, ndA, csr);
  k_p2b<<<NREL * NBIN, 256, 0, stream>>>(stOut, gCurOut, ns, ndA, wmv);
  k_prep<<<PREP_BLOCKS, 256, 0, stream>>>(x, xb, W1, b1, b2, W1T, bias1, bias2, W2, Wc, u);
  k_layer1<<<(N_NODES + 63) / 64, 256, 0, stream>>>(xb, csr, meta, W1T, bias1, h);
  k_mv<<<(N_NODES + 255) / 256, 256, 0, stream>>>(h, wmv, mv);
  k_final<<<1, 256, 0, stream>>>(mv, u, bias2, Wc, bc, out);
}

// Round 8
// 516.303 us; speedup vs baseline: 1.1605x; 1.0397x over previous
//
#include <hip/hip_runtime.h>

#define N_NODES 100000
#define NREL 6
#define NEDGE 400000
#define FDIM 128
#define HID 128

constexpr int RN = NREL * N_NODES;   // 600000
constexpr int NBIN = 391;            // ceil(100000 / 256) node bins of 256
constexpr int BINCAP = 1280;         // staging entries per (rel,bin); mean 1024, +8 sigma
constexpr int CSRCAP = 2304;         // int2 CSR entries per (rel,bin); max 1280+768 padded
constexpr int CHUNK = 8192;          // edges per phase-1 block
constexpr int NCHUNK = (NEDGE + CHUNK - 1) / CHUNK;  // 49

// k_prep block-range dispatch
constexpr int NB_XC = (N_NODES * 32) / 256;           // 12500 (exact)
constexpr int NB_WC = (NREL * FDIM * HID) / 256;      // 384 (exact)
constexpr int PREP_BLOCKS = NB_XC + NB_WC + NREL + 1;

typedef __attribute__((ext_vector_type(8))) short short8;
typedef __attribute__((ext_vector_type(4))) float f32x4;

__device__ __forceinline__ unsigned short f2bf(float f) {
  union { float f; unsigned int u; } v; v.f = f;
  unsigned int u = v.u;
  unsigned int r = (u + 0x7FFFu + ((u >> 16) & 1u)) >> 16;
  return (unsigned short)r;
}
__device__ __forceinline__ float bflo(unsigned int w) {
  union { unsigned int u; float f; } v; v.u = w << 16; return v.f;
}
__device__ __forceinline__ float bfhi(unsigned int w) {
  union { unsigned int u; float f; } v; v.u = w & 0xffff0000u; return v.f;
}

// ---------------- zero (cursors + mv only; tiny) ----------------
__global__ void k_zero(unsigned int* __restrict__ p, int nwords) {
  int id = blockIdx.x * blockDim.x + threadIdx.x;
  if (id < nwords) p[id] = 0u;
}

// ---------------- phase 1: LDS-binned staging, both directions ----------------
__global__ __launch_bounds__(256) void k_phase1(
    const int* __restrict__ src, const int* __restrict__ dst,
    int* __restrict__ gCurIn, int* __restrict__ gCurOut,
    unsigned int* __restrict__ stIn, unsigned int* __restrict__ stOut) {
  __shared__ int hIn[NBIN], hOut[NBIN], bIn[NBIN], bOut[NBIN];
  const int r = blockIdx.x / NCHUNK;
  const int c = blockIdx.x % NCHUNK;
  const int t = threadIdx.x;
  for (int i = t; i < NBIN; i += 256) { hIn[i] = 0; hOut[i] = 0; }
  __syncthreads();
  const int base = c * CHUNK;
  const int lim = min(CHUNK, NEDGE - base);
  const int* __restrict__ sR = src + r * NEDGE + base;
  const int* __restrict__ dR = dst + r * NEDGE + base;
  for (int i = t; i < lim; i += 256) {
    atomicAdd(&hIn[dR[i] >> 8], 1);
    atomicAdd(&hOut[sR[i] >> 8], 1);
  }
  __syncthreads();
  for (int i = t; i < NBIN; i += 256) {
    bIn[i]  = atomicAdd(&gCurIn[r * NBIN + i], hIn[i]);
    bOut[i] = atomicAdd(&gCurOut[r * NBIN + i], hOut[i]);
    hIn[i] = 0; hOut[i] = 0;
  }
  __syncthreads();
  for (int i = t; i < lim; i += 256) {
    const int s = sR[i], d = dR[i];
    const int bi = d >> 8, bo = s >> 8;
    const int pi = bIn[bi] + atomicAdd(&hIn[bi], 1);
    const int po = bOut[bo] + atomicAdd(&hOut[bo], 1);
    // pack: bits 17..24 = node-local (0..255), bits 0..16 = other endpoint
    if (pi < BINCAP)
      stIn[(size_t)(r * NBIN + bi) * BINCAP + pi] = ((unsigned)(d & 255) << 17) | (unsigned)s;
    if (po < BINCAP)
      stOut[(size_t)(r * NBIN + bo) * BINCAP + po] = ((unsigned)(s & 255) << 17) | (unsigned)d;
  }
}

// ---------------- phase 2a: out-degree count -> ns ----------------
__global__ __launch_bounds__(256) void k_p2a(const unsigned int* __restrict__ stOut,
                                             const int* __restrict__ gCurOut,
                                             float* __restrict__ ns) {
  __shared__ int cnt[256];
  const int rb = blockIdx.x;
  const int r = rb / NBIN, b = rb % NBIN;
  const int t = threadIdx.x;
  cnt[t] = 0;
  __syncthreads();
  const int m = min(gCurOut[rb], BINCAP);
  const unsigned int* __restrict__ st = stOut + (size_t)rb * BINCAP;
  for (int i = t; i < m; i += 256) atomicAdd(&cnt[st[i] >> 17], 1);
  __syncthreads();
  const int n = b * 256 + t;
  if (n < N_NODES) ns[r * N_NODES + n] = cnt[t] > 0 ? rsqrtf((float)cnt[t]) : 0.f;
}

// ---------------- phase 2b: in-count + scan -> meta, nd, dense padded CSR ----------------
__global__ __launch_bounds__(256) void k_p2in(const unsigned int* __restrict__ stIn,
                                              const int* __restrict__ gCurIn,
                                              const float* __restrict__ ns,
                                              int4* __restrict__ meta,
                                              float* __restrict__ ndA,
                                              int2* __restrict__ csr) {
  __shared__ int cnt[256], offs[256];
  __shared__ int wsum[4];
  const int rb = blockIdx.x;
  const int r = rb / NBIN, b = rb % NBIN;
  const int t = threadIdx.x;
  cnt[t] = 0;
  __syncthreads();
  const int m = min(gCurIn[rb], BINCAP);
  const unsigned int* __restrict__ st = stIn + (size_t)rb * BINCAP;
  for (int i = t; i < m; i += 256) atomicAdd(&cnt[st[i] >> 17], 1);
  __syncthreads();
  // exclusive scan of quad-padded counts
  const int lane = t & 63, wid = t >> 6;
  const int pc = (cnt[t] + 3) & ~3;
  int sum = pc;
#pragma unroll
  for (int o = 1; o < 64; o <<= 1) {
    int y = __shfl_up(sum, o);
    if (lane >= o) sum += y;
  }
  if (lane == 63) wsum[wid] = sum;
  __syncthreads();
  int wadd = 0;
  for (int w = 0; w < wid; ++w) wadd += wsum[w];
  offs[t] = sum - pc + wadd;
  __syncthreads();
  const int n = b * 256 + t;
  const int binBase = rb * CSRCAP;
  if (n < N_NODES) {
    const int d = cnt[t];
    const float nd = d > 0 ? rsqrtf((float)d) : 0.f;
    meta[r * N_NODES + n] = make_int4(d, binBase + offs[t], __float_as_int(nd), 0);
    ndA[r * N_NODES + n] = nd;
    int2* __restrict__ c = csr + binBase + offs[t];
    for (int e = d; e < ((d + 3) & ~3); ++e) c[e] = make_int2(0, 0);  // zero pads
  }
  __syncthreads();
  cnt[t] = 0;  // reuse as scatter cursors
  __syncthreads();
  const float* __restrict__ nsr = ns + r * N_NODES;
  for (int i = t; i < m; i += 256) {
    const unsigned int v = st[i];
    const int local = v >> 17;
    const int s = v & 0x1FFFF;
    const int pos = offs[local] + atomicAdd(&cnt[local], 1);
    csr[binBase + pos] = make_int2(s, __float_as_int(nsr[s]));
  }
}

// ---------------- phase 2c: coef = sum nd[dst] over out-edges -> wmv = ns*coef ----------------
__global__ __launch_bounds__(256) void k_p2b(const unsigned int* __restrict__ stOut,
                                             const int* __restrict__ gCurOut,
                                             const float* __restrict__ ns,
                                             const float* __restrict__ ndA,
                                             float* __restrict__ wmv) {
  __shared__ float fc[256];
  const int rb = blockIdx.x;
  const int r = rb / NBIN, b = rb % NBIN;
  const int t = threadIdx.x;
  fc[t] = 0.f;
  __syncthreads();
  const int m = min(gCurOut[rb], BINCAP);
  const unsigned int* __restrict__ st = stOut + (size_t)rb * BINCAP;
  const float* __restrict__ ndr = ndA + r * N_NODES;
  for (int i = t; i < m; i += 256) {
    const unsigned int v = st[i];
    atomicAdd(&fc[v >> 17], ndr[v & 0x1FFFF]);
  }
  __syncthreads();
  const int n = b * 256 + t;
  if (n < N_NODES) {
    const int rn = r * N_NODES + n;
    wmv[rn] = fc[t] * ns[rn];
  }
}

// ---------------- fused prep: x->bf16 | W1 transpose | u | biases ----------------
__global__ __launch_bounds__(256) void k_prep(
    const float* __restrict__ x, unsigned short* __restrict__ xb,
    const float* __restrict__ W1, const float* __restrict__ b1,
    const float* __restrict__ b2,
    unsigned short* __restrict__ W1T, float* __restrict__ bias1,
    float* __restrict__ bias2,
    const float* __restrict__ W2, const float* __restrict__ Wc,
    float* __restrict__ u) {
  const int b = blockIdx.x;
  const int t = threadIdx.x;
  if (b < NB_XC) {
    const int id = b * 256 + t;
    const float4 v = ((const float4*)x)[id];
    ushort4 o;
    o.x = f2bf(v.x); o.y = f2bf(v.y); o.z = f2bf(v.z); o.w = f2bf(v.w);
    ((ushort4*)xb)[id] = o;
  } else if (b < NB_XC + NB_WC) {
    const int id = (b - NB_XC) * 256 + t;
    const int r = id >> 14;
    const int rem = id & 16383;
    const int j = rem >> 7;
    const int k = rem & 127;
    W1T[id] = f2bf(W1[r * 16384 + k * 128 + j]);
  } else if (b < NB_XC + NB_WC + NREL) {
    const int r = b - (NB_XC + NB_WC);
    const int k = t >> 1;
    const int c = t & 1;
    const float* __restrict__ row = W2 + r * (HID * HID) + k * HID;
    float s = 0.f;
#pragma unroll 8
    for (int j = 0; j < HID; ++j) s = fmaf(row[j], Wc[j * 2 + c], s);
    u[(r * HID + k) * 2 + c] = s;
  } else {
    if (t < HID) {
      float s1 = 0.f, s2 = 0.f;
      for (int r = 0; r < NREL; ++r) {
        s1 += b1[r * HID + t];
        s2 += b2[r * HID + t];
      }
      bias1[t] = s1;
      bias2[t] = s2;
    }
  }
}

// ---------------- fused layer-1: 4-pass-fused branchless edge loop, MFMA ----------------
// Proven-best configuration (round 2: 262us, absmax 0.0). All 8 CSR loads +
// 16 gathers of a bi-iteration issue in one basic block; inactive passes are
// predicated via cndmask on BOTH the weight (0.0f) and the gather address
// (node-0 row, always valid). Never multiply-by-zero on raw CSR payloads
// (round-1 lesson: stale quads are uninitialized memory). CSR quads for bi+1
// software-pipelined before the FMAs of bi. Natural allocation 100 VGPR +
// 32 AGPR = 132 -> 2 waves/SIMD; rounds 3-4 proved both forcing a 128-cap
// (scratch spills, 358us) and restructuring for 96 regs (280us) are WORSE:
// deep per-wave MLP at 2 waves/SIMD is this structure's measured optimum.
__global__ __launch_bounds__(256, 2) void k_layer1(
    const unsigned short* __restrict__ xb,      // [N][128] bf16
    const int2* __restrict__ csr_ew,            // bin-region CSR {src, w}
    const int4* __restrict__ meta,              // [R][N] {d, absOff, nd_bits, -}
    const unsigned short* __restrict__ W1T,     // [R][128][128] bf16 (out, in)
    const float* __restrict__ bias1,
    unsigned short* __restrict__ h)             // [N][128] bf16
{
  __shared__ unsigned short zA[4][16][136];     // per-wave private slices
  const int tid = threadIdx.x;
  const int wave = tid >> 6;
  const int lane = tid & 63;
  const int sub = lane >> 4;
  const int flane = lane & 15;
  const int wnb = blockIdx.x * 64 + wave * 16;

  f32x4 acc[8];
#pragma unroll
  for (int t = 0; t < 8; ++t) acc[t] = (f32x4){0.f, 0.f, 0.f, 0.f};

  const int pn = wnb + flane;
  const bool pok = pn < N_NODES;
  const int pnc = pok ? pn : (N_NODES - 1);
  int4 mt = meta[pnc];
  if (!pok) { mt.x = 0; mt.z = 0; }

  const unsigned fo = (unsigned)(flane << 3);   // ushort offset within a 128-feat row

  for (int r = 0; r < NREL; ++r) {
    // per-pass row params (pass p of this wave handles rows p*4+sub)
    int d4[4], o4[4];
    float nd4[4];
#pragma unroll
    for (int p = 0; p < 4; ++p) {
      const int row = p * 4 + sub;
      d4[p] = __shfl(mt.x, row);
      o4[p] = __shfl(mt.y, row);
      nd4[p] = __int_as_float(__shfl(mt.z, row));
    }
    // wave-uniform max degree (mt replicated across the 4 subs)
    int dmax = mt.x;
#pragma unroll
    for (int s = 8; s >= 1; s >>= 1) dmax = max(dmax, __shfl_xor(dmax, s));
    const int nbmax = (dmax + 3) >> 2;

    float b[4][8];
#pragma unroll
    for (int p = 0; p < 4; ++p)
#pragma unroll
      for (int k = 0; k < 8; ++k) b[p][k] = 0.f;

    // preload CSR quads for bi=0 (always-valid memory; garbage contents for
    // d=0 rows are never consumed -- act-predication below)
    uint4 qa[4], qb[4];
#pragma unroll
    for (int p = 0; p < 4; ++p) {
      const uint4* __restrict__ lst = (const uint4*)(csr_ew + o4[p]);
      qa[p] = lst[0];
      qb[p] = lst[1];
    }

    for (int bi = 0; bi < nbmax; ++bi) {
      // predicated weight + gather-address extraction (cndmask, no branches)
      float w0[4], w1[4], w2[4], w3[4];
      unsigned a0[4], a1[4], a2[4], a3[4];
#pragma unroll
      for (int p = 0; p < 4; ++p) {
        const bool act = bi < ((d4[p] + 3) >> 2);
        w0[p] = act ? __uint_as_float(qa[p].y) : 0.f;
        w1[p] = act ? __uint_as_float(qa[p].w) : 0.f;
        w2[p] = act ? __uint_as_float(qb[p].y) : 0.f;
        w3[p] = act ? __uint_as_float(qb[p].w) : 0.f;
        a0[p] = act ? (((unsigned)qa[p].x << 7) + fo) : fo;
        a1[p] = act ? (((unsigned)qa[p].z << 7) + fo) : fo;
        a2[p] = act ? (((unsigned)qb[p].x << 7) + fo) : fo;
        a3[p] = act ? (((unsigned)qb[p].z << 7) + fo) : fo;
      }
      // issue all 16 gathers back-to-back
      uint4 v0[4], v1[4], v2[4], v3[4];
#pragma unroll
      for (int p = 0; p < 4; ++p) {
        v0[p] = *(const uint4*)(xb + a0[p]);
        v1[p] = *(const uint4*)(xb + a1[p]);
        v2[p] = *(const uint4*)(xb + a2[p]);
        v3[p] = *(const uint4*)(xb + a3[p]);
      }
      // software-pipeline: CSR quads for bi+1 (clamped to quad 0 when done;
      // valid memory, data never used)
#pragma unroll
      for (int p = 0; p < 4; ++p) {
        const int nb_p = (d4[p] + 3) >> 2;
        const int bn = bi + 1;
        const int qoff = o4[p] + ((bn < nb_p) ? (bn << 2) : 0);
        const uint4* __restrict__ lst = (const uint4*)(csr_ew + qoff);
        qa[p] = lst[0];
        qb[p] = lst[1];
      }
      // FMAs
#pragma unroll
      for (int p = 0; p < 4; ++p) {
#define ACC8(V, W) \
        b[p][0] = fmaf(bflo(V.x), W, b[p][0]); b[p][1] = fmaf(bfhi(V.x), W, b[p][1]); \
        b[p][2] = fmaf(bflo(V.y), W, b[p][2]); b[p][3] = fmaf(bfhi(V.y), W, b[p][3]); \
        b[p][4] = fmaf(bflo(V.z), W, b[p][4]); b[p][5] = fmaf(bfhi(V.z), W, b[p][5]); \
        b[p][6] = fmaf(bflo(V.w), W, b[p][6]); b[p][7] = fmaf(bfhi(V.w), W, b[p][7]);
        ACC8(v0[p], w0[p]) ACC8(v1[p], w1[p]) ACC8(v2[p], w2[p]) ACC8(v3[p], w3[p])
#undef ACC8
      }
    }

    // pack aggregated rows into zA
#pragma unroll
    for (int p = 0; p < 4; ++p) {
      const int row = p * 4 + sub;
      const float nd = nd4[p];
      uint4 pk;
      pk.x = (unsigned)f2bf(b[p][0] * nd) | ((unsigned)f2bf(b[p][1] * nd) << 16);
      pk.y = (unsigned)f2bf(b[p][2] * nd) | ((unsigned)f2bf(b[p][3] * nd) << 16);
      pk.z = (unsigned)f2bf(b[p][4] * nd) | ((unsigned)f2bf(b[p][5] * nd) << 16);
      pk.w = (unsigned)f2bf(b[p][6] * nd) | ((unsigned)f2bf(b[p][7] * nd) << 16);
      *(uint4*)(&zA[wave][row][flane * 8]) = pk;
    }
    int4 mtn = mt;
    if (r + 1 < NREL) {
      mtn = meta[(r + 1) * N_NODES + pnc];
      if (!pok) { mtn.x = 0; mtn.z = 0; }
    }
    const int m = lane & 15;
    const int qq = lane >> 4;
    const unsigned short* __restrict__ wr = W1T + r * (FDIM * HID);
#pragma unroll
    for (int kk = 0; kk < 4; ++kk) {
      const short8 af = *(const short8*)(&zA[wave][m][kk * 32 + qq * 8]);
#pragma unroll
      for (int t = 0; t < 8; ++t) {
        const short8 bfr = *(const short8*)(wr + (t * 16 + m) * 128 + kk * 32 + qq * 8);
        acc[t] = __builtin_amdgcn_mfma_f32_16x16x32_bf16(af, bfr, acc[t], 0, 0, 0);
      }
    }
    mt = mtn;
  }

  // epilogue: bias+relu, stage through zA (free after last MFMA; same-wave so
  // no barrier needed), then 16B-coalesced global stores
  const int col = lane & 15;
  const int rq = (lane >> 4) * 4;
#pragma unroll
  for (int t = 0; t < 8; ++t) {
    const float bsv = bias1[t * 16 + col];
#pragma unroll
    for (int rr = 0; rr < 4; ++rr) {
      float v = acc[t][rr] + bsv;
      v = fmaxf(v, 0.f);
      zA[wave][rq + rr][t * 16 + col] = f2bf(v);
    }
  }
#pragma unroll
  for (int rr2 = 0; rr2 < 4; ++rr2) {
    const int row = rr2 * 4 + sub;
    const int node = wnb + row;
    if (node < N_NODES) {
      const uint4 hv = *(const uint4*)(&zA[wave][row][flane * 8]);
      *(uint4*)(h + ((size_t)node << 7) + fo) = hv;
    }
  }
}

// ---------------- layer-2 folded: dense h stream with precomputed weights ----------------
__global__ __launch_bounds__(256) void k_mv(const unsigned short* __restrict__ h,
                                            const float* __restrict__ wmv,
                                            float* __restrict__ mv) {
  __shared__ float sh[16][136];
  const int sub = threadIdx.x >> 4;
  const int flane = threadIdx.x & 15;
  const unsigned fo = (unsigned)(flane << 3);
  float acc[NREL][8];
#pragma unroll
  for (int r = 0; r < NREL; ++r)
#pragma unroll
    for (int k = 0; k < 8; ++k) acc[r][k] = 0.f;
  const int nbase = blockIdx.x * 256 + sub * 16;
  for (int i = 0; i < 16; ++i) {
    const int n = nbase + i;
    if (n >= N_NODES) break;
    const uint4 hv = *(const uint4*)(h + ((size_t)n << 7) + fo);
    float hf[8];
    hf[0] = bflo(hv.x); hf[1] = bfhi(hv.x); hf[2] = bflo(hv.y); hf[3] = bfhi(hv.y);
    hf[4] = bflo(hv.z); hf[5] = bfhi(hv.z); hf[6] = bflo(hv.w); hf[7] = bfhi(hv.w);
#pragma unroll
    for (int r = 0; r < NREL; ++r) {
      const float w = wmv[r * N_NODES + n];
#pragma unroll
      for (int k = 0; k < 8; ++k) acc[r][k] = fmaf(w, hf[k], acc[r][k]);
    }
  }
  const float inv = 1.0f / (float)N_NODES;
  const int t = threadIdx.x;
#pragma unroll
  for (int r = 0; r < NREL; ++r) {
    __syncthreads();
#pragma unroll
    for (int k = 0; k < 8; ++k) sh[sub][flane * 8 + k] = acc[r][k];
    __syncthreads();
    if (t < 128) {
      float s = 0.f;
#pragma unroll
      for (int j = 0; j < 16; ++j) s += sh[j][t];
      atomicAdd(&mv[r * HID + t], s * inv);
    }
  }
}

// ---------------- final ----------------
__global__ __launch_bounds__(256) void k_final(const float* __restrict__ mv,
                                               const float* __restrict__ u,
                                               const float* __restrict__ bias2,
                                               const float* __restrict__ Wc,
                                               const float* __restrict__ bc,
                                               float* __restrict__ out) {
  __shared__ float r0[256], r1[256];
  const int t = threadIdx.x;
  float s0 = 0.f, s1 = 0.f;
  for (int rk = t; rk < NREL * HID; rk += 256) {
    const float m = mv[rk];
    s0 = fmaf(m, u[rk * 2], s0);
    s1 = fmaf(m, u[rk * 2 + 1], s1);
  }
  r0[t] = s0; r1[t] = s1;
  __syncthreads();
  for (int off = 128; off > 0; off >>= 1) {
    if (t < off) { r0[t] += r0[t + off]; r1[t] += r1[t + off]; }
    __syncthreads();
  }
  if (t == 0) {
    float t0 = bc[0], t1 = bc[1];
    for (int j = 0; j < HID; ++j) {
      const float b = bias2[j];
      t0 = fmaf(b, Wc[j * 2], t0);
      t1 = fmaf(b, Wc[j * 2 + 1], t1);
    }
    out[0] = r0[0] + t0;
    out[1] = r1[0] + t1;
  }
}

extern "C" void kernel_launch(void* const* d_in, const int* in_sizes, int n_in,
                              void* d_out, int out_size, void* d_ws, size_t ws_size,
                              hipStream_t stream) {
  (void)in_sizes; (void)n_in; (void)out_size; (void)ws_size;
  const float* x   = (const float*)d_in[0];
  const int* esrc  = (const int*)d_in[1];
  const int* edst  = (const int*)d_in[2];
  const float* W1  = (const float*)d_in[3];
  const float* b1  = (const float*)d_in[4];
  const float* W2  = (const float*)d_in[5];
  const float* b2  = (const float*)d_in[6];
  const float* Wc  = (const float*)d_in[7];
  const float* bc  = (const float*)d_in[8];
  float* out = (float*)d_out;

  char* p = (char*)d_ws;
  size_t off = 0;
  auto take = [&](size_t bytes) -> void* {
    void* q = p + off;
    off += (bytes + 255) & ~(size_t)255;
    return q;
  };
  // ---- zeroed region (cursors + mv; ~22 KB) ----
  int*   gCurIn  = (int*)take((size_t)NREL * NBIN * 4);
  int*   gCurOut = (int*)take((size_t)NREL * NBIN * 4);
  float* mv      = (float*)take((size_t)NREL * HID * 4);
  const size_t zero_bytes = off;
  // ---- non-zeroed region ----
  float* ns   = (float*)take((size_t)RN * 4);
  float* ndA  = (float*)take((size_t)RN * 4);
  float* wmv  = (float*)take((size_t)RN * 4);
  int4*  meta = (int4*)take((size_t)RN * 16);
  unsigned int* stIn  = (unsigned int*)take((size_t)NREL * NBIN * BINCAP * 4);  // 12 MB
  unsigned int* stOut = (unsigned int*)take((size_t)NREL * NBIN * BINCAP * 4);  // 12 MB
  int2* csr = (int2*)take((size_t)NREL * NBIN * CSRCAP * 8);                    // 43 MB
  unsigned short* W1T = (unsigned short*)take((size_t)NREL * FDIM * HID * 2);
  float* bias1 = (float*)take(HID * 4);
  float* bias2 = (float*)take(HID * 4);
  float* u     = (float*)take((size_t)NREL * HID * 2 * 4);
  unsigned short* h  = (unsigned short*)take((size_t)N_NODES * FDIM * 2);
  unsigned short* xb = (unsigned short*)take((size_t)N_NODES * FDIM * 2);

  const int zero_words = (int)(zero_bytes / 4);
  k_zero<<<(zero_words + 255) / 256, 256, 0, stream>>>((unsigned int*)d_ws, zero_words);
  k_phase1<<<NREL * NCHUNK, 256, 0, stream>>>(esrc, edst, gCurIn, gCurOut, stIn, stOut);
  k_p2a<<<NREL * NBIN, 256, 0, stream>>>(stOut, gCurOut, ns);
  k_p2in<<<NREL * NBIN, 256, 0, stream>>>(stIn, gCurIn, ns, meta, ndA, csr);
  k_p2b<<<NREL * NBIN, 256, 0, stream>>>(stOut, gCurOut, ns, ndA, wmv);
  k_prep<<<PREP_BLOCKS, 256, 0, stream>>>(x, xb, W1, b1, b2, W1T, bias1, bias2, W2, Wc, u);
  k_layer1<<<(N_NODES + 63) / 64, 256, 0, stream>>>(xb, csr, meta, W1T, bias1, h);
  k_mv<<<(N_NODES + 255) / 256, 256, 0, stream>>>(h, wmv, mv);
  k_final<<<1, 256, 0, stream>>>(mv, u, bias2, Wc, bc, out);
}

// Round 9
// 516.013 us; speedup vs baseline: 1.1612x; 1.0006x over previous
//
#include <hip/hip_runtime.h>

#define N_NODES 100000
#define NREL 6
#define NEDGE 400000
#define FDIM 128
#define HID 128

constexpr int RN = NREL * N_NODES;   // 600000
constexpr int NBIN = 391;            // ceil(100000 / 256) node bins of 256
constexpr int BINCAP = 1280;         // staging entries per (rel,bin); mean 1024, +8 sigma
constexpr int CSRCAP = 2304;         // int2 CSR entries per (rel,bin); max 1280+768 padded
constexpr int CHUNK = 8192;          // edges per phase-1 block
constexpr int NCHUNK = (NEDGE + CHUNK - 1) / CHUNK;  // 49

// k_prep block-range dispatch
constexpr int NB_XC = (N_NODES * 32) / 256;           // 12500 (exact)
constexpr int NB_WC = (NREL * FDIM * HID) / 256;      // 384 (exact)
constexpr int PREP_BLOCKS = NB_XC + NB_WC + NREL + 1;

typedef __attribute__((ext_vector_type(8))) short short8;
typedef __attribute__((ext_vector_type(4))) float f32x4;

__device__ __forceinline__ unsigned short f2bf(float f) {
  union { float f; unsigned int u; } v; v.f = f;
  unsigned int u = v.u;
  unsigned int r = (u + 0x7FFFu + ((u >> 16) & 1u)) >> 16;
  return (unsigned short)r;
}
__device__ __forceinline__ float bflo(unsigned int w) {
  union { unsigned int u; float f; } v; v.u = w << 16; return v.f;
}
__device__ __forceinline__ float bfhi(unsigned int w) {
  union { unsigned int u; float f; } v; v.u = w & 0xffff0000u; return v.f;
}

// ---------------- zero (cursors + mv only; tiny) ----------------
__global__ void k_zero(unsigned int* __restrict__ p, int nwords) {
  int id = blockIdx.x * blockDim.x + threadIdx.x;
  if (id < nwords) p[id] = 0u;
}

// ---------------- phase 1: LDS-binned staging, both directions ----------------
__global__ __launch_bounds__(256) void k_phase1(
    const int* __restrict__ src, const int* __restrict__ dst,
    int* __restrict__ gCurIn, int* __restrict__ gCurOut,
    unsigned int* __restrict__ stIn, unsigned int* __restrict__ stOut) {
  __shared__ int hIn[NBIN], hOut[NBIN], bIn[NBIN], bOut[NBIN];
  const int r = blockIdx.x / NCHUNK;
  const int c = blockIdx.x % NCHUNK;
  const int t = threadIdx.x;
  for (int i = t; i < NBIN; i += 256) { hIn[i] = 0; hOut[i] = 0; }
  __syncthreads();
  const int base = c * CHUNK;
  const int lim = min(CHUNK, NEDGE - base);
  const int* __restrict__ sR = src + r * NEDGE + base;
  const int* __restrict__ dR = dst + r * NEDGE + base;
  for (int i = t; i < lim; i += 256) {
    atomicAdd(&hIn[dR[i] >> 8], 1);
    atomicAdd(&hOut[sR[i] >> 8], 1);
  }
  __syncthreads();
  for (int i = t; i < NBIN; i += 256) {
    bIn[i]  = atomicAdd(&gCurIn[r * NBIN + i], hIn[i]);
    bOut[i] = atomicAdd(&gCurOut[r * NBIN + i], hOut[i]);
    hIn[i] = 0; hOut[i] = 0;
  }
  __syncthreads();
  for (int i = t; i < lim; i += 256) {
    const int s = sR[i], d = dR[i];
    const int bi = d >> 8, bo = s >> 8;
    const int pi = bIn[bi] + atomicAdd(&hIn[bi], 1);
    const int po = bOut[bo] + atomicAdd(&hOut[bo], 1);
    // pack: bits 17..24 = node-local (0..255), bits 0..16 = other endpoint
    if (pi < BINCAP)
      stIn[(size_t)(r * NBIN + bi) * BINCAP + pi] = ((unsigned)(d & 255) << 17) | (unsigned)s;
    if (po < BINCAP)
      stOut[(size_t)(r * NBIN + bo) * BINCAP + po] = ((unsigned)(s & 255) << 17) | (unsigned)d;
  }
}

// ---------------- phase 2a: out-degree count -> ns ----------------
__global__ __launch_bounds__(256) void k_p2a(const unsigned int* __restrict__ stOut,
                                             const int* __restrict__ gCurOut,
                                             float* __restrict__ ns) {
  __shared__ int cnt[256];
  const int rb = blockIdx.x;
  const int r = rb / NBIN, b = rb % NBIN;
  const int t = threadIdx.x;
  cnt[t] = 0;
  __syncthreads();
  const int m = min(gCurOut[rb], BINCAP);
  const unsigned int* __restrict__ st = stOut + (size_t)rb * BINCAP;
  for (int i = t; i < m; i += 256) atomicAdd(&cnt[st[i] >> 17], 1);
  __syncthreads();
  const int n = b * 256 + t;
  if (n < N_NODES) ns[r * N_NODES + n] = cnt[t] > 0 ? rsqrtf((float)cnt[t]) : 0.f;
}

// ---------------- phase 2b: in-count + scan -> meta, nd, dense padded CSR ----------------
__global__ __launch_bounds__(256) void k_p2in(const unsigned int* __restrict__ stIn,
                                              const int* __restrict__ gCurIn,
                                              const float* __restrict__ ns,
                                              int4* __restrict__ meta,
                                              float* __restrict__ ndA,
                                              int2* __restrict__ csr) {
  __shared__ int cnt[256], offs[256];
  __shared__ int wsum[4];
  const int rb = blockIdx.x;
  const int r = rb / NBIN, b = rb % NBIN;
  const int t = threadIdx.x;
  cnt[t] = 0;
  __syncthreads();
  const int m = min(gCurIn[rb], BINCAP);
  const unsigned int* __restrict__ st = stIn + (size_t)rb * BINCAP;
  for (int i = t; i < m; i += 256) atomicAdd(&cnt[st[i] >> 17], 1);
  __syncthreads();
  // exclusive scan of quad-padded counts
  const int lane = t & 63, wid = t >> 6;
  const int pc = (cnt[t] + 3) & ~3;
  int sum = pc;
#pragma unroll
  for (int o = 1; o < 64; o <<= 1) {
    int y = __shfl_up(sum, o);
    if (lane >= o) sum += y;
  }
  if (lane == 63) wsum[wid] = sum;
  __syncthreads();
  int wadd = 0;
  for (int w = 0; w < wid; ++w) wadd += wsum[w];
  offs[t] = sum - pc + wadd;
  __syncthreads();
  const int n = b * 256 + t;
  const int binBase = rb * CSRCAP;
  if (n < N_NODES) {
    const int d = cnt[t];
    const float nd = d > 0 ? rsqrtf((float)d) : 0.f;
    meta[r * N_NODES + n] = make_int4(d, binBase + offs[t], __float_as_int(nd), 0);
    ndA[r * N_NODES + n] = nd;
    int2* __restrict__ c = csr + binBase + offs[t];
    for (int e = d; e < ((d + 3) & ~3); ++e) c[e] = make_int2(0, 0);  // zero pads
  }
  __syncthreads();
  cnt[t] = 0;  // reuse as scatter cursors
  __syncthreads();
  const float* __restrict__ nsr = ns + r * N_NODES;
  for (int i = t; i < m; i += 256) {
    const unsigned int v = st[i];
    const int local = v >> 17;
    const int s = v & 0x1FFFF;
    const int pos = offs[local] + atomicAdd(&cnt[local], 1);
    csr[binBase + pos] = make_int2(s, __float_as_int(nsr[s]));
  }
}

// ---------------- phase 2c: coef = sum nd[dst] over out-edges -> wmv = ns*coef ----------------
__global__ __launch_bounds__(256) void k_p2b(const unsigned int* __restrict__ stOut,
                                             const int* __restrict__ gCurOut,
                                             const float* __restrict__ ns,
                                             const float* __restrict__ ndA,
                                             float* __restrict__ wmv) {
  __shared__ float fc[256];
  const int rb = blockIdx.x;
  const int r = rb / NBIN, b = rb % NBIN;
  const int t = threadIdx.x;
  fc[t] = 0.f;
  __syncthreads();
  const int m = min(gCurOut[rb], BINCAP);
  const unsigned int* __restrict__ st = stOut + (size_t)rb * BINCAP;
  const float* __restrict__ ndr = ndA + r * N_NODES;
  for (int i = t; i < m; i += 256) {
    const unsigned int v = st[i];
    atomicAdd(&fc[v >> 17], ndr[v & 0x1FFFF]);
  }
  __syncthreads();
  const int n = b * 256 + t;
  if (n < N_NODES) {
    const int rn = r * N_NODES + n;
    wmv[rn] = fc[t] * ns[rn];
  }
}

// ---------------- fused prep: x->bf16 | W1 transpose | u | biases ----------------
__global__ __launch_bounds__(256) void k_prep(
    const float* __restrict__ x, unsigned short* __restrict__ xb,
    const float* __restrict__ W1, const float* __restrict__ b1,
    const float* __restrict__ b2,
    unsigned short* __restrict__ W1T, float* __restrict__ bias1,
    float* __restrict__ bias2,
    const float* __restrict__ W2, const float* __restrict__ Wc,
    float* __restrict__ u) {
  const int b = blockIdx.x;
  const int t = threadIdx.x;
  if (b < NB_XC) {
    const int id = b * 256 + t;
    const float4 v = ((const float4*)x)[id];
    ushort4 o;
    o.x = f2bf(v.x); o.y = f2bf(v.y); o.z = f2bf(v.z); o.w = f2bf(v.w);
    ((ushort4*)xb)[id] = o;
  } else if (b < NB_XC + NB_WC) {
    const int id = (b - NB_XC) * 256 + t;
    const int r = id >> 14;
    const int rem = id & 16383;
    const int j = rem >> 7;
    const int k = rem & 127;
    W1T[id] = f2bf(W1[r * 16384 + k * 128 + j]);
  } else if (b < NB_XC + NB_WC + NREL) {
    const int r = b - (NB_XC + NB_WC);
    const int k = t >> 1;
    const int c = t & 1;
    const float* __restrict__ row = W2 + r * (HID * HID) + k * HID;
    float s = 0.f;
#pragma unroll 8
    for (int j = 0; j < HID; ++j) s = fmaf(row[j], Wc[j * 2 + c], s);
    u[(r * HID + k) * 2 + c] = s;
  } else {
    if (t < HID) {
      float s1 = 0.f, s2 = 0.f;
      for (int r = 0; r < NREL; ++r) {
        s1 += b1[r * HID + t];
        s2 += b2[r * HID + t];
      }
      bias1[t] = s1;
      bias2[t] = s2;
    }
  }
}

// ---------------- fused layer-1: 4-pass edge loop + MFMA, acc spilled to LDS --------
// Round-8 change (single variable vs the proven 254us/r8 kernel): the MFMA
// accumulator (acc[8] f32x4 = 32 regs) was live across the whole edge-gather
// phase but only USED in the short per-rel MFMA phase. It now round-trips
// through per-wave-private LDS (accL) between rels, freeing 32 VGPRs in the
// hot gather loop. Occupancy becomes LDS-bound, not VGPR-bound:
//   zA 17408 B + accL 4*64*36*4 = 36864 B -> 54272 B/block
//   -> 3 blocks/CU (162816 <= 163840) = 3 waves/SIMD (was 2), reg budget
//   512/3 = 170 >> demand (~120): no r3-style forced spill possible.
// accL row = 36 words: 144 B lane stride keeps b128 slots 16B-aligned and
// banks (4l+k)%32 perfectly balanced (the b128 minimum of 8 bank-cycles).
// Same full-depth 16-gather MLP as r2/r8; edge loop byte-identical.
__global__ __launch_bounds__(256, 3) void k_layer1(
    const unsigned short* __restrict__ xb,      // [N][128] bf16
    const int2* __restrict__ csr_ew,            // bin-region CSR {src, w}
    const int4* __restrict__ meta,              // [R][N] {d, absOff, nd_bits, -}
    const unsigned short* __restrict__ W1T,     // [R][128][128] bf16 (out, in)
    const float* __restrict__ bias1,
    unsigned short* __restrict__ h)             // [N][128] bf16
{
  __shared__ unsigned short zA[4][16][136];     // per-wave private slices
  __shared__ float accL[4][64][36];             // per-wave acc spill (32 used + 4 pad)
  const int tid = threadIdx.x;
  const int wave = tid >> 6;
  const int lane = tid & 63;
  const int sub = lane >> 4;
  const int flane = lane & 15;
  const int wnb = blockIdx.x * 64 + wave * 16;

  f32x4 acc[8];

  const int pn = wnb + flane;
  const bool pok = pn < N_NODES;
  const int pnc = pok ? pn : (N_NODES - 1);
  int4 mt = meta[pnc];
  if (!pok) { mt.x = 0; mt.z = 0; }

  const unsigned fo = (unsigned)(flane << 3);   // ushort offset within a 128-feat row

  for (int r = 0; r < NREL; ++r) {
    // per-pass row params (pass p of this wave handles rows p*4+sub)
    int d4[4], o4[4];
    float nd4[4];
#pragma unroll
    for (int p = 0; p < 4; ++p) {
      const int row = p * 4 + sub;
      d4[p] = __shfl(mt.x, row);
      o4[p] = __shfl(mt.y, row);
      nd4[p] = __int_as_float(__shfl(mt.z, row));
    }
    // wave-uniform max degree (mt replicated across the 4 subs)
    int dmax = mt.x;
#pragma unroll
    for (int s = 8; s >= 1; s >>= 1) dmax = max(dmax, __shfl_xor(dmax, s));
    const int nbmax = (dmax + 3) >> 2;

    float b[4][8];
#pragma unroll
    for (int p = 0; p < 4; ++p)
#pragma unroll
      for (int k = 0; k < 8; ++k) b[p][k] = 0.f;

    // preload CSR quads for bi=0 (always-valid memory; garbage contents for
    // d=0 rows are never consumed -- act-predication below)
    uint4 qa[4], qb[4];
#pragma unroll
    for (int p = 0; p < 4; ++p) {
      const uint4* __restrict__ lst = (const uint4*)(csr_ew + o4[p]);
      qa[p] = lst[0];
      qb[p] = lst[1];
    }

    for (int bi = 0; bi < nbmax; ++bi) {
      // predicated weight + gather-address extraction (cndmask, no branches)
      float w0[4], w1[4], w2[4], w3[4];
      unsigned a0[4], a1[4], a2[4], a3[4];
#pragma unroll
      for (int p = 0; p < 4; ++p) {
        const bool act = bi < ((d4[p] + 3) >> 2);
        w0[p] = act ? __uint_as_float(qa[p].y) : 0.f;
        w1[p] = act ? __uint_as_float(qa[p].w) : 0.f;
        w2[p] = act ? __uint_as_float(qb[p].y) : 0.f;
        w3[p] = act ? __uint_as_float(qb[p].w) : 0.f;
        a0[p] = act ? (((unsigned)qa[p].x << 7) + fo) : fo;
        a1[p] = act ? (((unsigned)qa[p].z << 7) + fo) : fo;
        a2[p] = act ? (((unsigned)qb[p].x << 7) + fo) : fo;
        a3[p] = act ? (((unsigned)qb[p].z << 7) + fo) : fo;
      }
      // issue all 16 gathers back-to-back
      uint4 v0[4], v1[4], v2[4], v3[4];
#pragma unroll
      for (int p = 0; p < 4; ++p) {
        v0[p] = *(const uint4*)(xb + a0[p]);
        v1[p] = *(const uint4*)(xb + a1[p]);
        v2[p] = *(const uint4*)(xb + a2[p]);
        v3[p] = *(const uint4*)(xb + a3[p]);
      }
      // software-pipeline: CSR quads for bi+1 (clamped to quad 0 when done;
      // valid memory, data never used)
#pragma unroll
      for (int p = 0; p < 4; ++p) {
        const int nb_p = (d4[p] + 3) >> 2;
        const int bn = bi + 1;
        const int qoff = o4[p] + ((bn < nb_p) ? (bn << 2) : 0);
        const uint4* __restrict__ lst = (const uint4*)(csr_ew + qoff);
        qa[p] = lst[0];
        qb[p] = lst[1];
      }
      // FMAs
#pragma unroll
      for (int p = 0; p < 4; ++p) {
#define ACC8(V, W) \
        b[p][0] = fmaf(bflo(V.x), W, b[p][0]); b[p][1] = fmaf(bfhi(V.x), W, b[p][1]); \
        b[p][2] = fmaf(bflo(V.y), W, b[p][2]); b[p][3] = fmaf(bfhi(V.y), W, b[p][3]); \
        b[p][4] = fmaf(bflo(V.z), W, b[p][4]); b[p][5] = fmaf(bfhi(V.z), W, b[p][5]); \
        b[p][6] = fmaf(bflo(V.w), W, b[p][6]); b[p][7] = fmaf(bfhi(V.w), W, b[p][7]);
        ACC8(v0[p], w0[p]) ACC8(v1[p], w1[p]) ACC8(v2[p], w2[p]) ACC8(v3[p], w3[p])
#undef ACC8
      }
    }

    // pack aggregated rows into zA
#pragma unroll
    for (int p = 0; p < 4; ++p) {
      const int row = p * 4 + sub;
      const float nd = nd4[p];
      uint4 pk;
      pk.x = (unsigned)f2bf(b[p][0] * nd) | ((unsigned)f2bf(b[p][1] * nd) << 16);
      pk.y = (unsigned)f2bf(b[p][2] * nd) | ((unsigned)f2bf(b[p][3] * nd) << 16);
      pk.z = (unsigned)f2bf(b[p][4] * nd) | ((unsigned)f2bf(b[p][5] * nd) << 16);
      pk.w = (unsigned)f2bf(b[p][6] * nd) | ((unsigned)f2bf(b[p][7] * nd) << 16);
      *(uint4*)(&zA[wave][row][flane * 8]) = pk;
    }
    int4 mtn = mt;
    if (r + 1 < NREL) {
      mtn = meta[(r + 1) * N_NODES + pnc];
      if (!pok) { mtn.x = 0; mtn.z = 0; }
    }
    // restore running accumulator (regs were free during the edge phase)
    if (r == 0) {
#pragma unroll
      for (int t = 0; t < 8; ++t) acc[t] = (f32x4){0.f, 0.f, 0.f, 0.f};
    } else {
#pragma unroll
      for (int t = 0; t < 8; ++t)
        acc[t] = *(const f32x4*)&accL[wave][lane][t * 4];
    }
    const int m = lane & 15;
    const int qq = lane >> 4;
    const unsigned short* __restrict__ wr = W1T + r * (FDIM * HID);
#pragma unroll
    for (int kk = 0; kk < 4; ++kk) {
      const short8 af = *(const short8*)(&zA[wave][m][kk * 32 + qq * 8]);
#pragma unroll
      for (int t = 0; t < 8; ++t) {
        const short8 bfr = *(const short8*)(wr + (t * 16 + m) * 128 + kk * 32 + qq * 8);
        acc[t] = __builtin_amdgcn_mfma_f32_16x16x32_bf16(af, bfr, acc[t], 0, 0, 0);
      }
    }
    // park accumulator in LDS for the next rel's edge phase (skip on last)
    if (r + 1 < NREL) {
#pragma unroll
      for (int t = 0; t < 8; ++t)
        *(f32x4*)&accL[wave][lane][t * 4] = acc[t];
    }
    mt = mtn;
  }

  // epilogue: bias+relu, stage through zA (free after last MFMA; same-wave so
  // no barrier needed), then 16B-coalesced global stores
  const int col = lane & 15;
  const int rq = (lane >> 4) * 4;
#pragma unroll
  for (int t = 0; t < 8; ++t) {
    const float bsv = bias1[t * 16 + col];
#pragma unroll
    for (int rr = 0; rr < 4; ++rr) {
      float v = acc[t][rr] + bsv;
      v = fmaxf(v, 0.f);
      zA[wave][rq + rr][t * 16 + col] = f2bf(v);
    }
  }
#pragma unroll
  for (int rr2 = 0; rr2 < 4; ++rr2) {
    const int row = rr2 * 4 + sub;
    const int node = wnb + row;
    if (node < N_NODES) {
      const uint4 hv = *(const uint4*)(&zA[wave][row][flane * 8]);
      *(uint4*)(h + ((size_t)node << 7) + fo) = hv;
    }
  }
}

// ---------------- layer-2 folded: dense h stream with precomputed weights ----------------
__global__ __launch_bounds__(256) void k_mv(const unsigned short* __restrict__ h,
                                            const float* __restrict__ wmv,
                                            float* __restrict__ mv) {
  __shared__ float sh[16][136];
  const int sub = threadIdx.x >> 4;
  const int flane = threadIdx.x & 15;
  const unsigned fo = (unsigned)(flane << 3);
  float acc[NREL][8];
#pragma unroll
  for (int r = 0; r < NREL; ++r)
#pragma unroll
    for (int k = 0; k < 8; ++k) acc[r][k] = 0.f;
  const int nbase = blockIdx.x * 256 + sub * 16;
  for (int i = 0; i < 16; ++i) {
    const int n = nbase + i;
    if (n >= N_NODES) break;
    const uint4 hv = *(const uint4*)(h + ((size_t)n << 7) + fo);
    float hf[8];
    hf[0] = bflo(hv.x); hf[1] = bfhi(hv.x); hf[2] = bflo(hv.y); hf[3] = bfhi(hv.y);
    hf[4] = bflo(hv.z); hf[5] = bfhi(hv.z); hf[6] = bflo(hv.w); hf[7] = bfhi(hv.w);
#pragma unroll
    for (int r = 0; r < NREL; ++r) {
      const float w = wmv[r * N_NODES + n];
#pragma unroll
      for (int k = 0; k < 8; ++k) acc[r][k] = fmaf(w, hf[k], acc[r][k]);
    }
  }
  const float inv = 1.0f / (float)N_NODES;
  const int t = threadIdx.x;
#pragma unroll
  for (int r = 0; r < NREL; ++r) {
    __syncthreads();
#pragma unroll
    for (int k = 0; k < 8; ++k) sh[sub][flane * 8 + k] = acc[r][k];
    __syncthreads();
    if (t < 128) {
      float s = 0.f;
#pragma unroll
      for (int j = 0; j < 16; ++j) s += sh[j][t];
      atomicAdd(&mv[r * HID + t], s * inv);
    }
  }
}

// ---------------- final ----------------
__global__ __launch_bounds__(256) void k_final(const float* __restrict__ mv,
                                               const float* __restrict__ u,
                                               const float* __restrict__ bias2,
                                               const float* __restrict__ Wc,
                                               const float* __restrict__ bc,
                                               float* __restrict__ out) {
  __shared__ float r0[256], r1[256];
  const int t = threadIdx.x;
  float s0 = 0.f, s1 = 0.f;
  for (int rk = t; rk < NREL * HID; rk += 256) {
    const float m = mv[rk];
    s0 = fmaf(m, u[rk * 2], s0);
    s1 = fmaf(m, u[rk * 2 + 1], s1);
  }
  r0[t] = s0; r1[t] = s1;
  __syncthreads();
  for (int off = 128; off > 0; off >>= 1) {
    if (t < off) { r0[t] += r0[t + off]; r1[t] += r1[t + off]; }
    __syncthreads();
  }
  if (t == 0) {
    float t0 = bc[0], t1 = bc[1];
    for (int j = 0; j < HID; ++j) {
      const float b = bias2[j];
      t0 = fmaf(b, Wc[j * 2], t0);
      t1 = fmaf(b, Wc[j * 2 + 1], t1);
    }
    out[0] = r0[0] + t0;
    out[1] = r1[0] + t1;
  }
}

extern "C" void kernel_launch(void* const* d_in, const int* in_sizes, int n_in,
                              void* d_out, int out_size, void* d_ws, size_t ws_size,
                              hipStream_t stream) {
  (void)in_sizes; (void)n_in; (void)out_size; (void)ws_size;
  const float* x   = (const float*)d_in[0];
  const int* esrc  = (const int*)d_in[1];
  const int* edst  = (const int*)d_in[2];
  const float* W1  = (const float*)d_in[3];
  const float* b1  = (const float*)d_in[4];
  const float* W2  = (const float*)d_in[5];
  const float* b2  = (const float*)d_in[6];
  const float* Wc  = (const float*)d_in[7];
  const float* bc  = (const float*)d_in[8];
  float* out = (float*)d_out;

  char* p = (char*)d_ws;
  size_t off = 0;
  auto take = [&](size_t bytes) -> void* {
    void* q = p + off;
    off += (bytes + 255) & ~(size_t)255;
    return q;
  };
  // ---- zeroed region (cursors + mv; ~22 KB) ----
  int*   gCurIn  = (int*)take((size_t)NREL * NBIN * 4);
  int*   gCurOut = (int*)take((size_t)NREL * NBIN * 4);
  float* mv      = (float*)take((size_t)NREL * HID * 4);
  const size_t zero_bytes = off;
  // ---- non-zeroed region ----
  float* ns   = (float*)take((size_t)RN * 4);
  float* ndA  = (float*)take((size_t)RN * 4);
  float* wmv  = (float*)take((size_t)RN * 4);
  int4*  meta = (int4*)take((size_t)RN * 16);
  unsigned int* stIn  = (unsigned int*)take((size_t)NREL * NBIN * BINCAP * 4);  // 12 MB
  unsigned int* stOut = (unsigned int*)take((size_t)NREL * NBIN * BINCAP * 4);  // 12 MB
  int2* csr = (int2*)take((size_t)NREL * NBIN * CSRCAP * 8);                    // 43 MB
  unsigned short* W1T = (unsigned short*)take((size_t)NREL * FDIM * HID * 2);
  float* bias1 = (float*)take(HID * 4);
  float* bias2 = (float*)take(HID * 4);
  float* u     = (float*)take((size_t)NREL * HID * 2 * 4);
  unsigned short* h  = (unsigned short*)take((size_t)N_NODES * FDIM * 2);
  unsigned short* xb = (unsigned short*)take((size_t)N_NODES * FDIM * 2);

  const int zero_words = (int)(zero_bytes / 4);
  k_zero<<<(zero_words + 255) / 256, 256, 0, stream>>>((unsigned int*)d_ws, zero_words);
  k_phase1<<<NREL * NCHUNK, 256, 0, stream>>>(esrc, edst, gCurIn, gCurOut, stIn, stOut);
  k_p2a<<<NREL * NBIN, 256, 0, stream>>>(stOut, gCurOut, ns);
  k_p2in<<<NREL * NBIN, 256, 0, stream>>>(stIn, gCurIn, ns, meta, ndA, csr);
  k_p2b<<<NREL * NBIN, 256, 0, stream>>>(stOut, gCurOut, ns, ndA, wmv);
  k_prep<<<PREP_BLOCKS, 256, 0, stream>>>(x, xb, W1, b1, b2, W1T, bias1, bias2, W2, Wc, u);
  k_layer1<<<(N_NODES + 63) / 64, 256, 0, stream>>>(xb, csr, meta, W1T, bias1, h);
  k_mv<<<(N_NODES + 255) / 256, 256, 0, stream>>>(h, wmv, mv);
  k_final<<<1, 256, 0, stream>>>(mv, u, bias2, Wc, bc, out);
}

// Round 10
// 501.458 us; speedup vs baseline: 1.1949x; 1.0290x over previous
//
#include <hip/hip_runtime.h>

#define N_NODES 100000
#define NREL 6
#define NEDGE 400000
#define FDIM 128
#define HID 128

constexpr int RN = NREL * N_NODES;   // 600000
constexpr int NBIN = 391;            // ceil(100000 / 256) node bins of 256
constexpr int BINCAP = 1280;         // staging entries per (rel,bin); mean 1024, +8 sigma
constexpr int CSRCAP = 2304;         // int2 CSR entries per (rel,bin); max 1280+768 padded
constexpr int CHUNK = 8192;          // edges per phase-1 block
constexpr int NCHUNK = (NEDGE + CHUNK - 1) / CHUNK;  // 49

// k_prep block-range dispatch
constexpr int NB_XC = (N_NODES * 32) / 256;           // 12500 (exact)
constexpr int NB_WC = (NREL * FDIM * HID) / 256;      // 384 (exact)
constexpr int PREP_BLOCKS = NB_XC + NB_WC + NREL + 1;

typedef __attribute__((ext_vector_type(8))) short short8;
typedef __attribute__((ext_vector_type(4))) float f32x4;

__device__ __forceinline__ unsigned short f2bf(float f) {
  union { float f; unsigned int u; } v; v.f = f;
  unsigned int u = v.u;
  unsigned int r = (u + 0x7FFFu + ((u >> 16) & 1u)) >> 16;
  return (unsigned short)r;
}
__device__ __forceinline__ float bflo(unsigned int w) {
  union { unsigned int u; float f; } v; v.u = w << 16; return v.f;
}
__device__ __forceinline__ float bfhi(unsigned int w) {
  union { unsigned int u; float f; } v; v.u = w & 0xffff0000u; return v.f;
}

// ---------------- zero (cursors + mv only; tiny) ----------------
__global__ void k_zero(unsigned int* __restrict__ p, int nwords) {
  int id = blockIdx.x * blockDim.x + threadIdx.x;
  if (id < nwords) p[id] = 0u;
}

// ---------------- phase 1: LDS-binned staging, both directions ----------------
__global__ __launch_bounds__(256) void k_phase1(
    const int* __restrict__ src, const int* __restrict__ dst,
    int* __restrict__ gCurIn, int* __restrict__ gCurOut,
    unsigned int* __restrict__ stIn, unsigned int* __restrict__ stOut) {
  __shared__ int hIn[NBIN], hOut[NBIN], bIn[NBIN], bOut[NBIN];
  const int r = blockIdx.x / NCHUNK;
  const int c = blockIdx.x % NCHUNK;
  const int t = threadIdx.x;
  for (int i = t; i < NBIN; i += 256) { hIn[i] = 0; hOut[i] = 0; }
  __syncthreads();
  const int base = c * CHUNK;
  const int lim = min(CHUNK, NEDGE - base);
  const int* __restrict__ sR = src + r * NEDGE + base;
  const int* __restrict__ dR = dst + r * NEDGE + base;
  for (int i = t; i < lim; i += 256) {
    atomicAdd(&hIn[dR[i] >> 8], 1);
    atomicAdd(&hOut[sR[i] >> 8], 1);
  }
  __syncthreads();
  for (int i = t; i < NBIN; i += 256) {
    bIn[i]  = atomicAdd(&gCurIn[r * NBIN + i], hIn[i]);
    bOut[i] = atomicAdd(&gCurOut[r * NBIN + i], hOut[i]);
    hIn[i] = 0; hOut[i] = 0;
  }
  __syncthreads();
  for (int i = t; i < lim; i += 256) {
    const int s = sR[i], d = dR[i];
    const int bi = d >> 8, bo = s >> 8;
    const int pi = bIn[bi] + atomicAdd(&hIn[bi], 1);
    const int po = bOut[bo] + atomicAdd(&hOut[bo], 1);
    // pack: bits 17..24 = node-local (0..255), bits 0..16 = other endpoint
    if (pi < BINCAP)
      stIn[(size_t)(r * NBIN + bi) * BINCAP + pi] = ((unsigned)(d & 255) << 17) | (unsigned)s;
    if (po < BINCAP)
      stOut[(size_t)(r * NBIN + bo) * BINCAP + po] = ((unsigned)(s & 255) << 17) | (unsigned)d;
  }
}

// ---------------- phase 2a: out-degree count -> ns ----------------
__global__ __launch_bounds__(256) void k_p2a(const unsigned int* __restrict__ stOut,
                                             const int* __restrict__ gCurOut,
                                             float* __restrict__ ns) {
  __shared__ int cnt[256];
  const int rb = blockIdx.x;
  const int r = rb / NBIN, b = rb % NBIN;
  const int t = threadIdx.x;
  cnt[t] = 0;
  __syncthreads();
  const int m = min(gCurOut[rb], BINCAP);
  const unsigned int* __restrict__ st = stOut + (size_t)rb * BINCAP;
  for (int i = t; i < m; i += 256) atomicAdd(&cnt[st[i] >> 17], 1);
  __syncthreads();
  const int n = b * 256 + t;
  if (n < N_NODES) ns[r * N_NODES + n] = cnt[t] > 0 ? rsqrtf((float)cnt[t]) : 0.f;
}

// ---------------- phase 2b: in-count + scan -> meta, nd, dense padded CSR ----------------
__global__ __launch_bounds__(256) void k_p2in(const unsigned int* __restrict__ stIn,
                                              const int* __restrict__ gCurIn,
                                              const float* __restrict__ ns,
                                              int4* __restrict__ meta,
                                              float* __restrict__ ndA,
                                              int2* __restrict__ csr) {
  __shared__ int cnt[256], offs[256];
  __shared__ int wsum[4];
  const int rb = blockIdx.x;
  const int r = rb / NBIN, b = rb % NBIN;
  const int t = threadIdx.x;
  cnt[t] = 0;
  __syncthreads();
  const int m = min(gCurIn[rb], BINCAP);
  const unsigned int* __restrict__ st = stIn + (size_t)rb * BINCAP;
  for (int i = t; i < m; i += 256) atomicAdd(&cnt[st[i] >> 17], 1);
  __syncthreads();
  // exclusive scan of quad-padded counts
  const int lane = t & 63, wid = t >> 6;
  const int pc = (cnt[t] + 3) & ~3;
  int sum = pc;
#pragma unroll
  for (int o = 1; o < 64; o <<= 1) {
    int y = __shfl_up(sum, o);
    if (lane >= o) sum += y;
  }
  if (lane == 63) wsum[wid] = sum;
  __syncthreads();
  int wadd = 0;
  for (int w = 0; w < wid; ++w) wadd += wsum[w];
  offs[t] = sum - pc + wadd;
  __syncthreads();
  const int n = b * 256 + t;
  const int binBase = rb * CSRCAP;
  if (n < N_NODES) {
    const int d = cnt[t];
    const float nd = d > 0 ? rsqrtf((float)d) : 0.f;
    meta[r * N_NODES + n] = make_int4(d, binBase + offs[t], __float_as_int(nd), 0);
    ndA[r * N_NODES + n] = nd;
    int2* __restrict__ c = csr + binBase + offs[t];
    for (int e = d; e < ((d + 3) & ~3); ++e) c[e] = make_int2(0, 0);  // zero pads
  }
  __syncthreads();
  cnt[t] = 0;  // reuse as scatter cursors
  __syncthreads();
  const float* __restrict__ nsr = ns + r * N_NODES;
  for (int i = t; i < m; i += 256) {
    const unsigned int v = st[i];
    const int local = v >> 17;
    const int s = v & 0x1FFFF;
    const int pos = offs[local] + atomicAdd(&cnt[local], 1);
    csr[binBase + pos] = make_int2(s, __float_as_int(nsr[s]));
  }
}

// ---------------- phase 2c: coef = sum nd[dst] over out-edges -> wmv = ns*coef ----------------
__global__ __launch_bounds__(256) void k_p2b(const unsigned int* __restrict__ stOut,
                                             const int* __restrict__ gCurOut,
                                             const float* __restrict__ ns,
                                             const float* __restrict__ ndA,
                                             float* __restrict__ wmv) {
  __shared__ float fc[256];
  const int rb = blockIdx.x;
  const int r = rb / NBIN, b = rb % NBIN;
  const int t = threadIdx.x;
  fc[t] = 0.f;
  __syncthreads();
  const int m = min(gCurOut[rb], BINCAP);
  const unsigned int* __restrict__ st = stOut + (size_t)rb * BINCAP;
  const float* __restrict__ ndr = ndA + r * N_NODES;
  for (int i = t; i < m; i += 256) {
    const unsigned int v = st[i];
    atomicAdd(&fc[v >> 17], ndr[v & 0x1FFFF]);
  }
  __syncthreads();
  const int n = b * 256 + t;
  if (n < N_NODES) {
    const int rn = r * N_NODES + n;
    wmv[rn] = fc[t] * ns[rn];
  }
}

// ---------------- fused prep: x->bf16 | W1 transpose | u | biases ----------------
__global__ __launch_bounds__(256) void k_prep(
    const float* __restrict__ x, unsigned short* __restrict__ xb,
    const float* __restrict__ W1, const float* __restrict__ b1,
    const float* __restrict__ b2,
    unsigned short* __restrict__ W1T, float* __restrict__ bias1,
    float* __restrict__ bias2,
    const float* __restrict__ W2, const float* __restrict__ Wc,
    float* __restrict__ u) {
  const int b = blockIdx.x;
  const int t = threadIdx.x;
  if (b < NB_XC) {
    const int id = b * 256 + t;
    const float4 v = ((const float4*)x)[id];
    ushort4 o;
    o.x = f2bf(v.x); o.y = f2bf(v.y); o.z = f2bf(v.z); o.w = f2bf(v.w);
    ((ushort4*)xb)[id] = o;
  } else if (b < NB_XC + NB_WC) {
    const int id = (b - NB_XC) * 256 + t;
    const int r = id >> 14;
    const int rem = id & 16383;
    const int j = rem >> 7;
    const int k = rem & 127;
    W1T[id] = f2bf(W1[r * 16384 + k * 128 + j]);
  } else if (b < NB_XC + NB_WC + NREL) {
    const int r = b - (NB_XC + NB_WC);
    const int k = t >> 1;
    const int c = t & 1;
    const float* __restrict__ row = W2 + r * (HID * HID) + k * HID;
    float s = 0.f;
#pragma unroll 8
    for (int j = 0; j < HID; ++j) s = fmaf(row[j], Wc[j * 2 + c], s);
    u[(r * HID + k) * 2 + c] = s;
  } else {
    if (t < HID) {
      float s1 = 0.f, s2 = 0.f;
      for (int r = 0; r < NREL; ++r) {
        s1 += b1[r * HID + t];
        s2 += b2[r * HID + t];
      }
      bias1[t] = s1;
      bias2[t] = s2;
    }
  }
}

// ---------------- fused layer-1: 4-pass edge loop + MFMA, acc spilled to LDS --------
// Round-9 lesson: LDS 54272 B/block left only 1 KB of the 160 KiB pool after
// 3 blocks (3x54272 = 162816 of 163840) -- runtime reserve/alloc-granularity
// blocked the 3rd block and occupancy stayed at 2 blocks/CU (19%), perf flat.
// This round: accL row stride 36 -> 34 words. accL = 4*64*34*4 = 34816 B,
// total = 17408 + 34816 = 52224 B/block -> 3 blocks = 156672 (7 KB slack;
// fits even under 2 KB alloc granularity). Bank check (b128, stride 34):
// first-word bank = (2*lane + 4k) % 32 -> only lane l vs l+16 alias = 2-way,
// which is free (m136). Registers (80 VGPR + 32 AGPR = 112) allow 4
// waves/SIMD, so LDS is the sole limiter -> 3 blocks/CU expected.
__global__ __launch_bounds__(256, 3) void k_layer1(
    const unsigned short* __restrict__ xb,      // [N][128] bf16
    const int2* __restrict__ csr_ew,            // bin-region CSR {src, w}
    const int4* __restrict__ meta,              // [R][N] {d, absOff, nd_bits, -}
    const unsigned short* __restrict__ W1T,     // [R][128][128] bf16 (out, in)
    const float* __restrict__ bias1,
    unsigned short* __restrict__ h)             // [N][128] bf16
{
  __shared__ unsigned short zA[4][16][136];     // per-wave private slices
  __shared__ float accL[4][64][34];             // per-wave acc spill (32 used + 2 pad)
  const int tid = threadIdx.x;
  const int wave = tid >> 6;
  const int lane = tid & 63;
  const int sub = lane >> 4;
  const int flane = lane & 15;
  const int wnb = blockIdx.x * 64 + wave * 16;

  f32x4 acc[8];

  const int pn = wnb + flane;
  const bool pok = pn < N_NODES;
  const int pnc = pok ? pn : (N_NODES - 1);
  int4 mt = meta[pnc];
  if (!pok) { mt.x = 0; mt.z = 0; }

  const unsigned fo = (unsigned)(flane << 3);   // ushort offset within a 128-feat row

  for (int r = 0; r < NREL; ++r) {
    // per-pass row params (pass p of this wave handles rows p*4+sub)
    int d4[4], o4[4];
    float nd4[4];
#pragma unroll
    for (int p = 0; p < 4; ++p) {
      const int row = p * 4 + sub;
      d4[p] = __shfl(mt.x, row);
      o4[p] = __shfl(mt.y, row);
      nd4[p] = __int_as_float(__shfl(mt.z, row));
    }
    // wave-uniform max degree (mt replicated across the 4 subs)
    int dmax = mt.x;
#pragma unroll
    for (int s = 8; s >= 1; s >>= 1) dmax = max(dmax, __shfl_xor(dmax, s));
    const int nbmax = (dmax + 3) >> 2;

    float b[4][8];
#pragma unroll
    for (int p = 0; p < 4; ++p)
#pragma unroll
      for (int k = 0; k < 8; ++k) b[p][k] = 0.f;

    // preload CSR quads for bi=0 (always-valid memory; garbage contents for
    // d=0 rows are never consumed -- act-predication below)
    uint4 qa[4], qb[4];
#pragma unroll
    for (int p = 0; p < 4; ++p) {
      const uint4* __restrict__ lst = (const uint4*)(csr_ew + o4[p]);
      qa[p] = lst[0];
      qb[p] = lst[1];
    }

    for (int bi = 0; bi < nbmax; ++bi) {
      // predicated weight + gather-address extraction (cndmask, no branches)
      float w0[4], w1[4], w2[4], w3[4];
      unsigned a0[4], a1[4], a2[4], a3[4];
#pragma unroll
      for (int p = 0; p < 4; ++p) {
        const bool act = bi < ((d4[p] + 3) >> 2);
        w0[p] = act ? __uint_as_float(qa[p].y) : 0.f;
        w1[p] = act ? __uint_as_float(qa[p].w) : 0.f;
        w2[p] = act ? __uint_as_float(qb[p].y) : 0.f;
        w3[p] = act ? __uint_as_float(qb[p].w) : 0.f;
        a0[p] = act ? (((unsigned)qa[p].x << 7) + fo) : fo;
        a1[p] = act ? (((unsigned)qa[p].z << 7) + fo) : fo;
        a2[p] = act ? (((unsigned)qb[p].x << 7) + fo) : fo;
        a3[p] = act ? (((unsigned)qb[p].z << 7) + fo) : fo;
      }
      // issue all 16 gathers back-to-back
      uint4 v0[4], v1[4], v2[4], v3[4];
#pragma unroll
      for (int p = 0; p < 4; ++p) {
        v0[p] = *(const uint4*)(xb + a0[p]);
        v1[p] = *(const uint4*)(xb + a1[p]);
        v2[p] = *(const uint4*)(xb + a2[p]);
        v3[p] = *(const uint4*)(xb + a3[p]);
      }
      // software-pipeline: CSR quads for bi+1 (clamped to quad 0 when done;
      // valid memory, data never used)
#pragma unroll
      for (int p = 0; p < 4; ++p) {
        const int nb_p = (d4[p] + 3) >> 2;
        const int bn = bi + 1;
        const int qoff = o4[p] + ((bn < nb_p) ? (bn << 2) : 0);
        const uint4* __restrict__ lst = (const uint4*)(csr_ew + qoff);
        qa[p] = lst[0];
        qb[p] = lst[1];
      }
      // FMAs
#pragma unroll
      for (int p = 0; p < 4; ++p) {
#define ACC8(V, W) \
        b[p][0] = fmaf(bflo(V.x), W, b[p][0]); b[p][1] = fmaf(bfhi(V.x), W, b[p][1]); \
        b[p][2] = fmaf(bflo(V.y), W, b[p][2]); b[p][3] = fmaf(bfhi(V.y), W, b[p][3]); \
        b[p][4] = fmaf(bflo(V.z), W, b[p][4]); b[p][5] = fmaf(bfhi(V.z), W, b[p][5]); \
        b[p][6] = fmaf(bflo(V.w), W, b[p][6]); b[p][7] = fmaf(bfhi(V.w), W, b[p][7]);
        ACC8(v0[p], w0[p]) ACC8(v1[p], w1[p]) ACC8(v2[p], w2[p]) ACC8(v3[p], w3[p])
#undef ACC8
      }
    }

    // pack aggregated rows into zA
#pragma unroll
    for (int p = 0; p < 4; ++p) {
      const int row = p * 4 + sub;
      const float nd = nd4[p];
      uint4 pk;
      pk.x = (unsigned)f2bf(b[p][0] * nd) | ((unsigned)f2bf(b[p][1] * nd) << 16);
      pk.y = (unsigned)f2bf(b[p][2] * nd) | ((unsigned)f2bf(b[p][3] * nd) << 16);
      pk.z = (unsigned)f2bf(b[p][4] * nd) | ((unsigned)f2bf(b[p][5] * nd) << 16);
      pk.w = (unsigned)f2bf(b[p][6] * nd) | ((unsigned)f2bf(b[p][7] * nd) << 16);
      *(uint4*)(&zA[wave][row][flane * 8]) = pk;
    }
    int4 mtn = mt;
    if (r + 1 < NREL) {
      mtn = meta[(r + 1) * N_NODES + pnc];
      if (!pok) { mtn.x = 0; mtn.z = 0; }
    }
    // restore running accumulator (regs were free during the edge phase)
    if (r == 0) {
#pragma unroll
      for (int t = 0; t < 8; ++t) acc[t] = (f32x4){0.f, 0.f, 0.f, 0.f};
    } else {
#pragma unroll
      for (int t = 0; t < 8; ++t)
        acc[t] = *(const f32x4*)&accL[wave][lane][t * 4];
    }
    const int m = lane & 15;
    const int qq = lane >> 4;
    const unsigned short* __restrict__ wr = W1T + r * (FDIM * HID);
#pragma unroll
    for (int kk = 0; kk < 4; ++kk) {
      const short8 af = *(const short8*)(&zA[wave][m][kk * 32 + qq * 8]);
#pragma unroll
      for (int t = 0; t < 8; ++t) {
        const short8 bfr = *(const short8*)(wr + (t * 16 + m) * 128 + kk * 32 + qq * 8);
        acc[t] = __builtin_amdgcn_mfma_f32_16x16x32_bf16(af, bfr, acc[t], 0, 0, 0);
      }
    }
    // park accumulator in LDS for the next rel's edge phase (skip on last)
    if (r + 1 < NREL) {
#pragma unroll
      for (int t = 0; t < 8; ++t)
        *(f32x4*)&accL[wave][lane][t * 4] = acc[t];
    }
    mt = mtn;
  }

  // epilogue: bias+relu, stage through zA (free after last MFMA; same-wave so
  // no barrier needed), then 16B-coalesced global stores
  const int col = lane & 15;
  const int rq = (lane >> 4) * 4;
#pragma unroll
  for (int t = 0; t < 8; ++t) {
    const float bsv = bias1[t * 16 + col];
#pragma unroll
    for (int rr = 0; rr < 4; ++rr) {
      float v = acc[t][rr] + bsv;
      v = fmaxf(v, 0.f);
      zA[wave][rq + rr][t * 16 + col] = f2bf(v);
    }
  }
#pragma unroll
  for (int rr2 = 0; rr2 < 4; ++rr2) {
    const int row = rr2 * 4 + sub;
    const int node = wnb + row;
    if (node < N_NODES) {
      const uint4 hv = *(const uint4*)(&zA[wave][row][flane * 8]);
      *(uint4*)(h + ((size_t)node << 7) + fo) = hv;
    }
  }
}

// ---------------- layer-2 folded: dense h stream with precomputed weights ----------------
__global__ __launch_bounds__(256) void k_mv(const unsigned short* __restrict__ h,
                                            const float* __restrict__ wmv,
                                            float* __restrict__ mv) {
  __shared__ float sh[16][136];
  const int sub = threadIdx.x >> 4;
  const int flane = threadIdx.x & 15;
  const unsigned fo = (unsigned)(flane << 3);
  float acc[NREL][8];
#pragma unroll
  for (int r = 0; r < NREL; ++r)
#pragma unroll
    for (int k = 0; k < 8; ++k) acc[r][k] = 0.f;
  const int nbase = blockIdx.x * 256 + sub * 16;
  for (int i = 0; i < 16; ++i) {
    const int n = nbase + i;
    if (n >= N_NODES) break;
    const uint4 hv = *(const uint4*)(h + ((size_t)n << 7) + fo);
    float hf[8];
    hf[0] = bflo(hv.x); hf[1] = bfhi(hv.x); hf[2] = bflo(hv.y); hf[3] = bfhi(hv.y);
    hf[4] = bflo(hv.z); hf[5] = bfhi(hv.z); hf[6] = bflo(hv.w); hf[7] = bfhi(hv.w);
#pragma unroll
    for (int r = 0; r < NREL; ++r) {
      const float w = wmv[r * N_NODES + n];
#pragma unroll
      for (int k = 0; k < 8; ++k) acc[r][k] = fmaf(w, hf[k], acc[r][k]);
    }
  }
  const float inv = 1.0f / (float)N_NODES;
  const int t = threadIdx.x;
#pragma unroll
  for (int r = 0; r < NREL; ++r) {
    __syncthreads();
#pragma unroll
    for (int k = 0; k < 8; ++k) sh[sub][flane * 8 + k] = acc[r][k];
    __syncthreads();
    if (t < 128) {
      float s = 0.f;
#pragma unroll
      for (int j = 0; j < 16; ++j) s += sh[j][t];
      atomicAdd(&mv[r * HID + t], s * inv);
    }
  }
}

// ---------------- final ----------------
__global__ __launch_bounds__(256) void k_final(const float* __restrict__ mv,
                                               const float* __restrict__ u,
                                               const float* __restrict__ bias2,
                                               const float* __restrict__ Wc,
                                               const float* __restrict__ bc,
                                               float* __restrict__ out) {
  __shared__ float r0[256], r1[256];
  const int t = threadIdx.x;
  float s0 = 0.f, s1 = 0.f;
  for (int rk = t; rk < NREL * HID; rk += 256) {
    const float m = mv[rk];
    s0 = fmaf(m, u[rk * 2], s0);
    s1 = fmaf(m, u[rk * 2 + 1], s1);
  }
  r0[t] = s0; r1[t] = s1;
  __syncthreads();
  for (int off = 128; off > 0; off >>= 1) {
    if (t < off) { r0[t] += r0[t + off]; r1[t] += r1[t + off]; }
    __syncthreads();
  }
  if (t == 0) {
    float t0 = bc[0], t1 = bc[1];
    for (int j = 0; j < HID; ++j) {
      const float b = bias2[j];
      t0 = fmaf(b, Wc[j * 2], t0);
      t1 = fmaf(b, Wc[j * 2 + 1], t1);
    }
    out[0] = r0[0] + t0;
    out[1] = r1[0] + t1;
  }
}

extern "C" void kernel_launch(void* const* d_in, const int* in_sizes, int n_in,
                              void* d_out, int out_size, void* d_ws, size_t ws_size,
                              hipStream_t stream) {
  (void)in_sizes; (void)n_in; (void)out_size; (void)ws_size;
  const float* x   = (const float*)d_in[0];
  const int* esrc  = (const int*)d_in[1];
  const int* edst  = (const int*)d_in[2];
  const float* W1  = (const float*)d_in[3];
  const float* b1  = (const float*)d_in[4];
  const float* W2  = (const float*)d_in[5];
  const float* b2  = (const float*)d_in[6];
  const float* Wc  = (const float*)d_in[7];
  const float* bc  = (const float*)d_in[8];
  float* out = (float*)d_out;

  char* p = (char*)d_ws;
  size_t off = 0;
  auto take = [&](size_t bytes) -> void* {
    void* q = p + off;
    off += (bytes + 255) & ~(size_t)255;
    return q;
  };
  // ---- zeroed region (cursors + mv; ~22 KB) ----
  int*   gCurIn  = (int*)take((size_t)NREL * NBIN * 4);
  int*   gCurOut = (int*)take((size_t)NREL * NBIN * 4);
  float* mv      = (float*)take((size_t)NREL * HID * 4);
  const size_t zero_bytes = off;
  // ---- non-zeroed region ----
  float* ns   = (float*)take((size_t)RN * 4);
  float* ndA  = (float*)take((size_t)RN * 4);
  float* wmv  = (float*)take((size_t)RN * 4);
  int4*  meta = (int4*)take((size_t)RN * 16);
  unsigned int* stIn  = (unsigned int*)take((size_t)NREL * NBIN * BINCAP * 4);  // 12 MB
  unsigned int* stOut = (unsigned int*)take((size_t)NREL * NBIN * BINCAP * 4);  // 12 MB
  int2* csr = (int2*)take((size_t)NREL * NBIN * CSRCAP * 8);                    // 43 MB
  unsigned short* W1T = (unsigned short*)take((size_t)NREL * FDIM * HID * 2);
  float* bias1 = (float*)take(HID * 4);
  float* bias2 = (float*)take(HID * 4);
  float* u     = (float*)take((size_t)NREL * HID * 2 * 4);
  unsigned short* h  = (unsigned short*)take((size_t)N_NODES * FDIM * 2);
  unsigned short* xb = (unsigned short*)take((size_t)N_NODES * FDIM * 2);

  const int zero_words = (int)(zero_bytes / 4);
  k_zero<<<(zero_words + 255) / 256, 256, 0, stream>>>((unsigned int*)d_ws, zero_words);
  k_phase1<<<NREL * NCHUNK, 256, 0, stream>>>(esrc, edst, gCurIn, gCurOut, stIn, stOut);
  k_p2a<<<NREL * NBIN, 256, 0, stream>>>(stOut, gCurOut, ns);
  k_p2in<<<NREL * NBIN, 256, 0, stream>>>(stIn, gCurIn, ns, meta, ndA, csr);
  k_p2b<<<NREL * NBIN, 256, 0, stream>>>(stOut, gCurOut, ns, ndA, wmv);
  k_prep<<<PREP_BLOCKS, 256, 0, stream>>>(x, xb, W1, b1, b2, W1T, bias1, bias2, W2, Wc, u);
  k_layer1<<<(N_NODES + 63) / 64, 256, 0, stream>>>(xb, csr, meta, W1T, bias1, h);
  k_mv<<<(N_NODES + 255) / 256, 256, 0, stream>>>(h, wmv, mv);
  k_final<<<1, 256, 0, stream>>>(mv, u, bias2, Wc, bc, out);
}